// Round 6
// baseline (535.761 us; speedup 1.0000x reference)
//
#include <hip/hip_runtime.h>
#include <math.h>

typedef unsigned short us;
typedef short s16x8 __attribute__((ext_vector_type(8)));
typedef float f32x4 __attribute__((ext_vector_type(4)));

#define EPSV 1e-5f

static __device__ inline us f2bf(float f) {            // RNE f32->bf16 (finite inputs)
  union { float f; unsigned u; } v; v.f = f;
  unsigned r = v.u + 0x7fffu + ((v.u >> 16) & 1u);
  return (us)(r >> 16);
}

// conv1 A-fragment k->offset table (k = kg*8+j; c=k/9,t=k%9,ki=t/3,kj=t%3;
// off = c*1024+ki*32+kj; k>=27 -> 3072 = zero pad region)
#define SET8(o,a,b,c,d,e,f,g,h) {o[0]=a;o[1]=b;o[2]=c;o[3]=d;o[4]=e;o[5]=f;o[6]=g;o[7]=h;}
static __device__ inline void c1_offsets(int kg, int* offs) {
  switch (kg) {
    case 0: SET8(offs, 0, 1, 2, 32, 33, 34, 64, 65); break;
    case 1: SET8(offs, 66, 1024, 1025, 1026, 1056, 1057, 1058, 1088); break;
    case 2: SET8(offs, 1089, 1090, 2048, 2049, 2050, 2080, 2081, 2082); break;
    default: SET8(offs, 2112, 2113, 2114, 3072, 3072, 3072, 3072, 3072); break;
  }
}

union AU { s16x8 v; us e[8]; };

// ---------------------------------------------------------------- K0: preconvert conv weights
__global__ __launch_bounds__(256) void prep_weights(
    const float* __restrict__ w1, const float* __restrict__ w2,
    const float* __restrict__ w3, us* __restrict__ wt1L,
    us* __restrict__ wt2L, us* __restrict__ wt3L) {
  const int tid = blockIdx.x * 256 + threadIdx.x;
  if (tid < 1280) {
    const int oc = tid / 40, k = tid % 40;
    wt1L[tid] = (k < 27) ? f2bf(w1[oc * 27 + k]) : (us)0;
  }
  for (int i = tid; i < 11520; i += gridDim.x * 256) {
    const int row = i / 40, col = i % 40;
    const int tap = row >> 5, oc = row & 31;
    wt2L[i] = (col < 32) ? f2bf(w2[oc * 288 + col * 9 + tap]) : (us)0;
    wt3L[i] = (col < 32) ? f2bf(w3[oc * 288 + col * 9 + tap]) : (us)0;
  }
}

// ---------------------------------------------------------------- finalize: partials -> {scale, shift}
__global__ __launch_bounds__(256) void finalize_stats(
    const float* __restrict__ part, const float* __restrict__ g,
    const float* __restrict__ bb, float cnt, float* __restrict__ stats) {
  __shared__ float red[256];
  const int tid = threadIdx.x;
  const int ch = tid & 63, grp = tid >> 6;
  float s = 0.f;
  for (int i = grp; i < 2048; i += 4) s += part[i * 64 + ch];
  red[tid] = s;
  __syncthreads();
  if (tid < 64) red[tid] = red[tid] + red[64 + tid] + red[128 + tid] + red[192 + tid];
  __syncthreads();
  if (tid < 32) {
    const float mean = red[tid] / cnt;
    const float var = red[32 + tid] / cnt - mean * mean;
    const float sc = g[tid] * rsqrtf(var + EPSV);
    stats[tid] = sc;
    stats[32 + tid] = bb[tid] - mean * sc;
  }
}

// ---------------------------------------------------------------- K1: conv1 stats only
__global__ __launch_bounds__(256) void conv1_stats(
    const float* __restrict__ x, const us* __restrict__ wt1L,
    const float* __restrict__ cb, float* __restrict__ part1) {
  __shared__ __align__(16) us xsb[4096];      // [3][32][32] bf16 + zero pad
  __shared__ __align__(16) us wt1[1280];      // [32][40]
  __shared__ float csum[32], css[32];
  const int n = blockIdx.x, tid = threadIdx.x;
  const int wave = tid >> 6, lane = tid & 63, row16 = lane & 15, kg = lane >> 4;
  const float4* xp = (const float4*)(x + (size_t)n * 3072);
  for (int i = tid; i < 768; i += 256) {
    const float4 v = xp[i];
    const unsigned lo = f2bf(v.x) | ((unsigned)f2bf(v.y) << 16);
    const unsigned hi = f2bf(v.z) | ((unsigned)f2bf(v.w) << 16);
    *(uint2*)&xsb[i * 4] = make_uint2(lo, hi);
  }
  if (tid < 256) *(uint2*)&xsb[3072 + tid * 4] = make_uint2(0, 0);
  if (tid < 160) ((uint4*)wt1)[tid] = ((const uint4*)wt1L)[tid];
  if (tid < 32) { csum[tid] = 0.f; css[tid] = 0.f; }
  __syncthreads();
  int offs[8]; c1_offsets(kg, offs);
  const s16x8 bf0 = *(const s16x8*)&wt1[row16 * 40 + kg * 8];
  const s16x8 bf1 = *(const s16x8*)&wt1[(16 + row16) * 40 + kg * 8];
  const float bias0 = cb[row16], bias1 = cb[16 + row16];
  float s0 = 0.f, ss0 = 0.f, s1 = 0.f, ss1 = 0.f;
  for (int t = wave; t < 60; t += 4) {        // tile = 2 rows x 8 cols
    const int ip = t >> 2, cg = t & 3;
    const int ai = 2 * ip + (row16 >> 3), aj = cg * 8 + (row16 & 7);
    const int base = (aj < 30) ? (ai * 32 + aj) : 0;
    AU a;
#pragma unroll
    for (int q = 0; q < 8; ++q) a.e[q] = xsb[base + offs[q]];
    f32x4 acc0 = {bias0, bias0, bias0, bias0};
    f32x4 acc1 = {bias1, bias1, bias1, bias1};
    acc0 = __builtin_amdgcn_mfma_f32_16x16x32_bf16(a.v, bf0, acc0, 0, 0, 0);
    acc1 = __builtin_amdgcn_mfma_f32_16x16x32_bf16(a.v, bf1, acc1, 0, 0, 0);
#pragma unroll
    for (int r = 0; r < 4; ++r) {
      const int jc = cg * 8 + (kg & 1) * 4 + r;
      if (jc < 30) {
        s0 += acc0[r]; ss0 += acc0[r] * acc0[r];
        s1 += acc1[r]; ss1 += acc1[r] * acc1[r];
      }
    }
  }
  s0 += __shfl_down(s0, 32); s0 += __shfl_down(s0, 16);
  ss0 += __shfl_down(ss0, 32); ss0 += __shfl_down(ss0, 16);
  s1 += __shfl_down(s1, 32); s1 += __shfl_down(s1, 16);
  ss1 += __shfl_down(ss1, 32); ss1 += __shfl_down(ss1, 16);
  if (lane < 16) {
    atomicAdd(&csum[row16], s0); atomicAdd(&css[row16], ss0);
    atomicAdd(&csum[16 + row16], s1); atomicAdd(&css[16 + row16], ss1);
  }
  __syncthreads();
  if (tid < 32) {
    part1[n * 64 + tid] = csum[tid];
    part1[n * 64 + 32 + tid] = css[tid];
  }
}

// ---------------------------------------------------------------- K2: conv1 recompute + bn1+relu+pool1 -> p1 (bf16) + conv2 partials
__global__ __launch_bounds__(256) void conv1_apply_conv2_stats(
    const float* __restrict__ x, const us* __restrict__ wt1L,
    const float* __restrict__ cb1, const float* __restrict__ stats1,
    const us* __restrict__ wt2L, const float* __restrict__ cb2,
    float* __restrict__ part2, us* __restrict__ p1g) {
  __shared__ __align__(16) us xsb[4096];
  __shared__ __align__(16) us wt1[1280];
  __shared__ __align__(16) us p1b[9000];      // [225][40]
  __shared__ __align__(16) us wt2[11520];     // [9][32][40]
  __shared__ float scS[32], shS[32], csum[32], css[32];
  const int n = blockIdx.x, tid = threadIdx.x;
  const int wave = tid >> 6, lane = tid & 63, row16 = lane & 15, kg = lane >> 4;
  const float4* xp = (const float4*)(x + (size_t)n * 3072);
  for (int i = tid; i < 768; i += 256) {
    const float4 v = xp[i];
    const unsigned lo = f2bf(v.x) | ((unsigned)f2bf(v.y) << 16);
    const unsigned hi = f2bf(v.z) | ((unsigned)f2bf(v.w) << 16);
    *(uint2*)&xsb[i * 4] = make_uint2(lo, hi);
  }
  if (tid < 256) *(uint2*)&xsb[3072 + tid * 4] = make_uint2(0, 0);
  if (tid < 160) ((uint4*)wt1)[tid] = ((const uint4*)wt1L)[tid];
  for (int i = tid; i < 1440; i += 256) ((uint4*)wt2)[i] = ((const uint4*)wt2L)[i];
  if (tid < 32) {
    scS[tid] = stats1[tid]; shS[tid] = stats1[32 + tid];
    csum[tid] = 0.f; css[tid] = 0.f;
  }
  __syncthreads();
  int offs[8]; c1_offsets(kg, offs);
  {
    const s16x8 bf0 = *(const s16x8*)&wt1[row16 * 40 + kg * 8];
    const s16x8 bf1 = *(const s16x8*)&wt1[(16 + row16) * 40 + kg * 8];
    const float bias0 = cb1[row16], bias1 = cb1[16 + row16];
    const float sc0 = scS[row16], sh0 = shS[row16];
    const float sc1 = scS[16 + row16], sh1 = shS[16 + row16];
    for (int t = wave; t < 60; t += 4) {
      const int ip = t >> 2, cg = t & 3;
      const int ai = 2 * ip + (row16 >> 3), aj = cg * 8 + (row16 & 7);
      const int base = (aj < 30) ? (ai * 32 + aj) : 0;
      AU a;
#pragma unroll
      for (int q = 0; q < 8; ++q) a.e[q] = xsb[base + offs[q]];
      f32x4 acc0 = {bias0, bias0, bias0, bias0};
      f32x4 acc1 = {bias1, bias1, bias1, bias1};
      acc0 = __builtin_amdgcn_mfma_f32_16x16x32_bf16(a.v, bf0, acc0, 0, 0, 0);
      acc1 = __builtin_amdgcn_mfma_f32_16x16x32_bf16(a.v, bf1, acc1, 0, 0, 0);
      float v0[4], v1[4];
#pragma unroll
      for (int r = 0; r < 4; ++r) {
        v0[r] = fmaxf(acc0[r] * sc0 + sh0, 0.f);
        v1[r] = fmaxf(acc1[r] * sc1 + sh1, 0.f);
      }
      const float a01_0 = v0[0] + v0[1], a23_0 = v0[2] + v0[3];
      const float a01_1 = v1[0] + v1[1], a23_1 = v1[2] + v1[3];
      const float p01_0 = __shfl_xor(a01_0, 32), p23_0 = __shfl_xor(a23_0, 32);
      const float p01_1 = __shfl_xor(a01_1, 32), p23_1 = __shfl_xor(a23_1, 32);
      if (kg < 2) {                           // rows 2ip (this) + 2ip+1 (partner)
        const int cpa = kg * 2;
        const int oa = ip * 15 + cg * 4 + cpa;
        p1b[oa * 40 + row16] = f2bf((a01_0 + p01_0) * 0.25f);
        p1b[oa * 40 + 16 + row16] = f2bf((a01_1 + p01_1) * 0.25f);
        if (cg < 3 || kg == 0) {              // cpb=3 at cg=3 is out of range
          const int ob = oa + 1;
          p1b[ob * 40 + row16] = f2bf((a23_0 + p23_0) * 0.25f);
          p1b[ob * 40 + 16 + row16] = f2bf((a23_1 + p23_1) * 0.25f);
        }
      }
    }
  }
  __syncthreads();
  // write p1 (bf16) coalesced
  for (int i = tid; i < 900; i += 256) {
    const uint4 v = *(const uint4*)&p1b[(i >> 2) * 40 + (i & 3) * 8];
    *(uint4*)(p1g + (size_t)n * 7200 + i * 8) = v;
  }
  // conv2 stats from LDS p1
  int inb[3];
#pragma unroll
  for (int m = 0; m < 3; ++m) {
    int pixA = (wave + 4 * m) * 16 + row16;
    if (pixA >= 169) pixA = 0;
    const int oi = pixA / 13, oj = pixA - 13 * oi;
    inb[m] = oi * 15 + oj;
  }
  const float b20 = cb2[row16], b21 = cb2[16 + row16];
  f32x4 acc[3][2];
#pragma unroll
  for (int m = 0; m < 3; ++m) {
    acc[m][0] = {b20, b20, b20, b20};
    acc[m][1] = {b21, b21, b21, b21};
  }
#pragma unroll
  for (int tap = 0; tap < 9; ++tap) {
    const int ki = tap / 3, kj = tap % 3;
    const s16x8 bf0 = *(const s16x8*)&wt2[(tap * 32 + row16) * 40 + kg * 8];
    const s16x8 bf1 = *(const s16x8*)&wt2[(tap * 32 + 16 + row16) * 40 + kg * 8];
#pragma unroll
    for (int m = 0; m < 3; ++m) {
      const s16x8 a = *(const s16x8*)&p1b[(inb[m] + ki * 15 + kj) * 40 + kg * 8];
      acc[m][0] = __builtin_amdgcn_mfma_f32_16x16x32_bf16(a, bf0, acc[m][0], 0, 0, 0);
      acc[m][1] = __builtin_amdgcn_mfma_f32_16x16x32_bf16(a, bf1, acc[m][1], 0, 0, 0);
    }
  }
  float s0 = 0.f, ss0 = 0.f, s1 = 0.f, ss1 = 0.f;
#pragma unroll
  for (int m = 0; m < 3; ++m)
#pragma unroll
    for (int r = 0; r < 4; ++r) {
      const int pix = (wave + 4 * m) * 16 + kg * 4 + r;
      if (pix < 169) {
        const float u0 = acc[m][0][r], u1 = acc[m][1][r];
        s0 += u0; ss0 += u0 * u0; s1 += u1; ss1 += u1 * u1;
      }
    }
  s0 += __shfl_down(s0, 32); s0 += __shfl_down(s0, 16);
  ss0 += __shfl_down(ss0, 32); ss0 += __shfl_down(ss0, 16);
  s1 += __shfl_down(s1, 32); s1 += __shfl_down(s1, 16);
  ss1 += __shfl_down(ss1, 32); ss1 += __shfl_down(ss1, 16);
  if (lane < 16) {
    atomicAdd(&csum[row16], s0); atomicAdd(&css[row16], ss0);
    atomicAdd(&csum[16 + row16], s1); atomicAdd(&css[16 + row16], ss1);
  }
  __syncthreads();
  if (tid < 32) {
    part2[n * 64 + tid] = csum[tid];
    part2[n * 64 + 32 + tid] = css[tid];
  }
}

// ---------------------------------------------------------------- K3: conv2 recompute + bn2+relu+pool2 -> p2 (bf16) + conv3 partials
__global__ __launch_bounds__(256) void conv2_apply_conv3_stats(
    const us* __restrict__ p1g, const us* __restrict__ wt2L,
    const float* __restrict__ cb2, const float* __restrict__ stats2,
    const us* __restrict__ wt3L, const float* __restrict__ cb3,
    float* __restrict__ part3, us* __restrict__ p2g) {
  __shared__ __align__(16) us p1b[9000];      // [225][40]
  __shared__ __align__(16) us wt2[11520];
  __shared__ __align__(16) float p2a[1188];   // [36][33] f32 accum
  __shared__ __align__(16) us p2b[1440];      // [36][40]
  __shared__ float scS[32], shS[32], csum[32], css[32];
  const int n = blockIdx.x, tid = threadIdx.x;
  const int wave = tid >> 6, lane = tid & 63, row16 = lane & 15, kg = lane >> 4;
  for (int i = tid; i < 900; i += 256) {
    const uint4 v = *(const uint4*)(p1g + (size_t)n * 7200 + i * 8);
    *(uint4*)&p1b[(i >> 2) * 40 + (i & 3) * 8] = v;
  }
  for (int i = tid; i < 1440; i += 256) ((uint4*)wt2)[i] = ((const uint4*)wt2L)[i];
  for (int i = tid; i < 1188; i += 256) p2a[i] = 0.f;
  if (tid < 32) {
    scS[tid] = stats2[tid]; shS[tid] = stats2[32 + tid];
    csum[tid] = 0.f; css[tid] = 0.f;
  }
  __syncthreads();
  int inb[3];
#pragma unroll
  for (int m = 0; m < 3; ++m) {
    int pixA = (wave + 4 * m) * 16 + row16;
    if (pixA >= 169) pixA = 0;
    const int oi = pixA / 13, oj = pixA - 13 * oi;
    inb[m] = oi * 15 + oj;
  }
  const float b20 = cb2[row16], b21 = cb2[16 + row16];
  f32x4 acc[3][2];
#pragma unroll
  for (int m = 0; m < 3; ++m) {
    acc[m][0] = {b20, b20, b20, b20};
    acc[m][1] = {b21, b21, b21, b21};
  }
#pragma unroll
  for (int tap = 0; tap < 9; ++tap) {
    const int ki = tap / 3, kj = tap % 3;
    const s16x8 bf0 = *(const s16x8*)&wt2[(tap * 32 + row16) * 40 + kg * 8];
    const s16x8 bf1 = *(const s16x8*)&wt2[(tap * 32 + 16 + row16) * 40 + kg * 8];
#pragma unroll
    for (int m = 0; m < 3; ++m) {
      const s16x8 a = *(const s16x8*)&p1b[(inb[m] + ki * 15 + kj) * 40 + kg * 8];
      acc[m][0] = __builtin_amdgcn_mfma_f32_16x16x32_bf16(a, bf0, acc[m][0], 0, 0, 0);
      acc[m][1] = __builtin_amdgcn_mfma_f32_16x16x32_bf16(a, bf1, acc[m][1], 0, 0, 0);
    }
  }
  const float sc0 = scS[row16], sh0 = shS[row16];
  const float sc1 = scS[16 + row16], sh1 = shS[16 + row16];
#pragma unroll
  for (int m = 0; m < 3; ++m)
#pragma unroll
    for (int r = 0; r < 4; ++r) {
      const int pix = (wave + 4 * m) * 16 + kg * 4 + r;
      if (pix < 169) {
        const int i = pix / 13, j = pix - 13 * i;
        if (i < 12 && j < 12) {
          const int op = (i >> 1) * 6 + (j >> 1);
          atomicAdd(&p2a[op * 33 + row16], fmaxf(acc[m][0][r] * sc0 + sh0, 0.f) * 0.25f);
          atomicAdd(&p2a[op * 33 + 16 + row16], fmaxf(acc[m][1][r] * sc1 + sh1, 0.f) * 0.25f);
        }
      }
    }
  __syncthreads();
  if (tid < 144) {
    const int row = tid >> 2, col = (tid & 3) * 8;
    uint4 v;
    us tmp[8];
#pragma unroll
    for (int q = 0; q < 8; ++q) tmp[q] = f2bf(p2a[row * 33 + col + q]);
    v.x = tmp[0] | ((unsigned)tmp[1] << 16); v.y = tmp[2] | ((unsigned)tmp[3] << 16);
    v.z = tmp[4] | ((unsigned)tmp[5] << 16); v.w = tmp[6] | ((unsigned)tmp[7] << 16);
    *(uint4*)&p2b[row * 40 + col] = v;
    *(uint4*)(p2g + (size_t)n * 1152 + tid * 8) = v;
  }
  __syncthreads();
  if (wave < 2) {                              // conv3 stats (16 out px, 1 m-tile)
    const int ocb = wave * 16;
    const int inb3 = (row16 >> 2) * 6 + (row16 & 3);
    const float b3 = cb3[ocb + row16];
    f32x4 a3 = {b3, b3, b3, b3};
#pragma unroll
    for (int tap = 0; tap < 9; ++tap) {
      const int ki = tap / 3, kj = tap % 3;
      const s16x8 bf = *(const s16x8*)&wt3L[(tap * 32 + ocb + row16) * 40 + kg * 8];
      const s16x8 a = *(const s16x8*)&p2b[(inb3 + ki * 6 + kj) * 40 + kg * 8];
      a3 = __builtin_amdgcn_mfma_f32_16x16x32_bf16(a, bf, a3, 0, 0, 0);
    }
    float s = a3[0] + a3[1] + a3[2] + a3[3];
    float ss = a3[0]*a3[0] + a3[1]*a3[1] + a3[2]*a3[2] + a3[3]*a3[3];
    s += __shfl_down(s, 32); s += __shfl_down(s, 16);
    ss += __shfl_down(ss, 32); ss += __shfl_down(ss, 16);
    if (lane < 16) { atomicAdd(&csum[ocb + row16], s); atomicAdd(&css[ocb + row16], ss); }
  }
  __syncthreads();
  if (tid < 32) {
    part3[n * 64 + tid] = csum[tid];
    part3[n * 64 + 32 + tid] = css[tid];
  }
}

// ---------------------------------------------------------------- K4: conv3 recompute + bn3+relu+pool3 -> h0 (8 samples/block)
__global__ __launch_bounds__(256) void conv3_apply(
    const us* __restrict__ p2g, const us* __restrict__ wt3L,
    const float* __restrict__ cb3, const float* __restrict__ stats3,
    float* __restrict__ h0g) {
  __shared__ __align__(16) us p2L[11520];      // [8][36][40]
  __shared__ __align__(16) us wt3[11520];
  __shared__ float scS[32], shS[32];
  __shared__ float h0a[1024];
  const int n0 = blockIdx.x * 8, tid = threadIdx.x;
  const int wave = tid >> 6, lane = tid & 63, row16 = lane & 15, kg = lane >> 4;
  for (int i = tid; i < 1152; i += 256) {
    const int s = i / 144, ci = i - s * 144;
    const uint4 v = *(const uint4*)(p2g + (size_t)n0 * 1152 + i * 8);
    *(uint4*)&p2L[(s * 36 + (ci >> 2)) * 40 + (ci & 3) * 8] = v;
  }
  for (int i = tid; i < 1440; i += 256) ((uint4*)wt3)[i] = ((const uint4*)wt3L)[i];
  for (int i = tid; i < 1024; i += 256) h0a[i] = 0.f;
  if (tid < 32) { scS[tid] = stats3[tid]; shS[tid] = stats3[32 + tid]; }
  __syncthreads();
  const int inb3 = (row16 >> 2) * 6 + (row16 & 3);
  const float b30 = cb3[row16], b31 = cb3[16 + row16];
  f32x4 accA[2][2];
#pragma unroll
  for (int si = 0; si < 2; ++si) {
    accA[si][0] = {b30, b30, b30, b30};
    accA[si][1] = {b31, b31, b31, b31};
  }
#pragma unroll
  for (int tap = 0; tap < 9; ++tap) {
    const int ki = tap / 3, kj = tap % 3;
    const s16x8 bf0 = *(const s16x8*)&wt3[(tap * 32 + row16) * 40 + kg * 8];
    const s16x8 bf1 = *(const s16x8*)&wt3[(tap * 32 + 16 + row16) * 40 + kg * 8];
#pragma unroll
    for (int si = 0; si < 2; ++si) {
      const int s = wave + 4 * si;
      const s16x8 a = *(const s16x8*)&p2L[(s * 36 + inb3 + ki * 6 + kj) * 40 + kg * 8];
      accA[si][0] = __builtin_amdgcn_mfma_f32_16x16x32_bf16(a, bf0, accA[si][0], 0, 0, 0);
      accA[si][1] = __builtin_amdgcn_mfma_f32_16x16x32_bf16(a, bf1, accA[si][1], 0, 0, 0);
    }
  }
  const float sc0 = scS[row16], sh0 = shS[row16];
  const float sc1 = scS[16 + row16], sh1 = shS[16 + row16];
#pragma unroll
  for (int si = 0; si < 2; ++si) {
    const int s = wave + 4 * si;
#pragma unroll
    for (int r = 0; r < 4; ++r) {
      const int pix = kg * 4 + r;
      const int op = ((pix >> 2) >> 1) * 2 + ((pix & 3) >> 1);
      atomicAdd(&h0a[s * 128 + row16 * 4 + op], fmaxf(accA[si][0][r] * sc0 + sh0, 0.f) * 0.25f);
      atomicAdd(&h0a[s * 128 + (16 + row16) * 4 + op], fmaxf(accA[si][1][r] * sc1 + sh1, 0.f) * 0.25f);
    }
  }
  __syncthreads();
  ((float4*)(h0g + (size_t)n0 * 128))[tid] = ((const float4*)h0a)[tid];
}

// ---------------------------------------------------------------- K5: MFMA routed MLP
#define STR 136
__global__ __launch_bounds__(256) void mlp2_kernel(
    const float* __restrict__ h0, const float* __restrict__ traj,
    const float* __restrict__ eW, const float* __restrict__ eb,
    const float* __restrict__ oW, const float* __restrict__ ob,
    float* __restrict__ out) {
  __shared__ __align__(16) us wexp[3 * 128 * STR];
  __shared__ __align__(16) us owl[112 * STR];
  __shared__ __align__(16) us htile[4][16 * STR];
  __shared__ float ebl[384];
  __shared__ float obl[112];
  const int tid = threadIdx.x, wave = tid >> 6, lane = tid & 63;
  const int row16 = lane & 15, kg = lane >> 4;
  const int rbase = blockIdx.x * 64 + wave * 16;
  for (int i = tid; i < 12288; i += 256) {
    const int e = i >> 12, rem = i & 4095, o = rem >> 5, d4 = (rem & 31) * 4;
    const float4 v = *(const float4*)(eW + ((e * 128 + o) * 128 + d4));
    const unsigned lo = f2bf(v.x) | ((unsigned)f2bf(v.y) << 16);
    const unsigned hi = f2bf(v.z) | ((unsigned)f2bf(v.w) << 16);
    *(uint2*)&wexp[(e * 128 + o) * STR + d4] = make_uint2(lo, hi);
  }
  for (int i = tid; i < 112 * 32; i += 256) {
    const int cls = i >> 5, d4 = (i & 31) * 4;
    float4 v = make_float4(0.f, 0.f, 0.f, 0.f);
    if (cls < 100) v = *(const float4*)(oW + cls * 128 + d4);
    const unsigned lo = f2bf(v.x) | ((unsigned)f2bf(v.y) << 16);
    const unsigned hi = f2bf(v.z) | ((unsigned)f2bf(v.w) << 16);
    *(uint2*)&owl[cls * STR + d4] = make_uint2(lo, hi);
  }
  for (int i = tid; i < 384; i += 256) ebl[i] = eb[i];
  if (tid < 112) obl[tid] = (tid < 100) ? ob[tid] : 0.f;
  us* ht = &htile[wave][0];
  for (int i = lane; i < 256; i += 64) {
    const int row = i >> 4, d8 = (i & 15) * 8;
    const int rowg = rbase + row;
    const float4 v0 = *(const float4*)(h0 + (size_t)(rowg >> 1) * 128 + d8);
    const float4 v1 = *(const float4*)(h0 + (size_t)(rowg >> 1) * 128 + d8 + 4);
    uint4 p;
    p.x = f2bf(v0.x) | ((unsigned)f2bf(v0.y) << 16);
    p.y = f2bf(v0.z) | ((unsigned)f2bf(v0.w) << 16);
    p.z = f2bf(v1.x) | ((unsigned)f2bf(v1.y) << 16);
    p.w = f2bf(v1.z) | ((unsigned)f2bf(v1.w) << 16);
    *(uint4*)&ht[row * STR + d8] = p;
  }
  __syncthreads();
  float accv[8][4];
#pragma unroll
  for (int ct = 0; ct < 8; ++ct)
#pragma unroll
    for (int r = 0; r < 4; ++r) {
      const int rowg = rbase + kg * 4 + r;
      accv[ct][r] = h0[(size_t)(rowg >> 1) * 128 + ct * 16 + row16];
    }
  for (int d = 0; d < 3; ++d) {
    int sel[4];
#pragma unroll
    for (int r = 0; r < 4; ++r) {
      const int rowg = rbase + kg * 4 + r;
      const float4 t4 = *(const float4*)(traj + d * 16384 + rowg * 4);
      int s = 0; float mx = t4.x;
      if (t4.y > mx) { mx = t4.y; s = 1; }
      if (t4.z > mx) { mx = t4.z; s = 2; }
      if (t4.w > mx) { mx = t4.w; s = 3; }
      sel[r] = s;
    }
    s16x8 a[4];
#pragma unroll
    for (int kc = 0; kc < 4; ++kc)
      a[kc] = *(const s16x8*)&ht[row16 * STR + kc * 32 + kg * 8];
    float newacc[8][4];
#pragma unroll
    for (int ct = 0; ct < 8; ++ct)
#pragma unroll
      for (int r = 0; r < 4; ++r)
        newacc[ct][r] = (sel[r] == 3) ? accv[ct][r] : 0.f;
#pragma unroll
    for (int e = 0; e < 3; ++e) {
#pragma unroll
      for (int ct = 0; ct < 8; ++ct) {
        f32x4 t = {0.f, 0.f, 0.f, 0.f};
#pragma unroll
        for (int kc = 0; kc < 4; ++kc) {
          const s16x8 b = *(const s16x8*)&wexp[(e * 128 + ct * 16 + row16) * STR + kc * 32 + kg * 8];
          t = __builtin_amdgcn_mfma_f32_16x16x32_bf16(a[kc], b, t, 0, 0, 0);
        }
        const float bias = ebl[e * 128 + ct * 16 + row16];
#pragma unroll
        for (int r = 0; r < 4; ++r)
          if (sel[r] == e) newacc[ct][r] = t[r] + bias;
      }
    }
#pragma unroll
    for (int ct = 0; ct < 8; ++ct)
#pragma unroll
      for (int r = 0; r < 4; ++r) {
        float v = newacc[ct][r];
        if (d < 2) v = fmaxf(v, 0.f);
        accv[ct][r] = v;
        ht[(kg * 4 + r) * STR + ct * 16 + row16] = f2bf(v);
      }
  }
  s16x8 a[4];
#pragma unroll
  for (int kc = 0; kc < 4; ++kc)
    a[kc] = *(const s16x8*)&ht[row16 * STR + kc * 32 + kg * 8];
  float preds[7][4];
#pragma unroll
  for (int ct = 0; ct < 7; ++ct) {
    f32x4 t = {0.f, 0.f, 0.f, 0.f};
#pragma unroll
    for (int kc = 0; kc < 4; ++kc) {
      const s16x8 b = *(const s16x8*)&owl[(ct * 16 + row16) * STR + kc * 32 + kg * 8];
      t = __builtin_amdgcn_mfma_f32_16x16x32_bf16(a[kc], b, t, 0, 0, 0);
    }
    const float bias = obl[ct * 16 + row16];
#pragma unroll
    for (int r = 0; r < 4; ++r) preds[ct][r] = t[r] + bias;
  }
  const bool v6 = (96 + row16) < 100;
#pragma unroll
  for (int r = 0; r < 4; ++r) {
    float mx = -INFINITY;
#pragma unroll
    for (int ct = 0; ct < 7; ++ct)
      if (ct < 6 || v6) mx = fmaxf(mx, preds[ct][r]);
    mx = fmaxf(mx, __shfl_xor(mx, 1)); mx = fmaxf(mx, __shfl_xor(mx, 2));
    mx = fmaxf(mx, __shfl_xor(mx, 4)); mx = fmaxf(mx, __shfl_xor(mx, 8));
    float s = 0.f;
#pragma unroll
    for (int ct = 0; ct < 7; ++ct)
      if (ct < 6 || v6) s += expf(preds[ct][r] - mx);
    s += __shfl_xor(s, 1); s += __shfl_xor(s, 2);
    s += __shfl_xor(s, 4); s += __shfl_xor(s, 8);
    const float lg = mx + logf(s);
    const int rowg = rbase + kg * 4 + r;
#pragma unroll
    for (int ct = 0; ct < 7; ++ct)
      if (ct < 6 || v6) out[(size_t)rowg * 100 + ct * 16 + row16] = preds[ct][r] - lg;
  }
}

// ---------------------------------------------------------------- launch
extern "C" void kernel_launch(void* const* d_in, const int* in_sizes, int n_in,
                              void* d_out, int out_size, void* d_ws, size_t ws_size,
                              hipStream_t stream) {
  const float* x     = (const float*)d_in[0];
  const float* traj  = (const float*)d_in[1];
  const float* score = (const float*)d_in[2];
  const float* cw1 = (const float*)d_in[3];
  const float* cb1 = (const float*)d_in[4];
  const float* g1  = (const float*)d_in[5];
  const float* bb1 = (const float*)d_in[6];
  const float* cw2 = (const float*)d_in[7];
  const float* cb2 = (const float*)d_in[8];
  const float* g2  = (const float*)d_in[9];
  const float* bb2 = (const float*)d_in[10];
  const float* cw3 = (const float*)d_in[11];
  const float* cb3 = (const float*)d_in[12];
  const float* g3  = (const float*)d_in[13];
  const float* bb3 = (const float*)d_in[14];
  const float* eW  = (const float*)d_in[15];
  const float* eb  = (const float*)d_in[16];
  const float* oW  = (const float*)d_in[17];
  const float* ob  = (const float*)d_in[18];
  float* out = (float*)d_out;

  char* ws = (char*)d_ws;
  float* stats1 = (float*)ws;                    // 64 f32 {sc,sh}
  float* stats2 = (float*)(ws + 256);
  float* stats3 = (float*)(ws + 512);
  us* wt1L = (us*)(ws + 1024);                   // 1280 us
  us* wt2L = (us*)(ws + 4096);                   // 11520 us = 23040 B
  us* wt3L = (us*)(ws + 4096 + 23040);           // 11520 us
  us* p1g  = (us*)(ws + 65536);                  // bf16 [2048][225][32] = 29,491,200 B
  us* p2g  = (us*)(ws + 65536 + 29491200);       // bf16 [2048][36][32]  =  4,718,592 B
  float* h0g = (float*)(ws + 65536 + 29491200 + 4718592);  // f32 [2048][128] = 1 MB
  char* pbase = ws + 65536 + 29491200 + 4718592 + 1048576;
  float* part1 = (float*)pbase;                  // [2048][64] f32 = 512 KB
  float* part2 = (float*)(pbase + 524288);
  float* part3 = (float*)(pbase + 1048576);

  prep_weights<<<12, 256, 0, stream>>>(cw1, cw2, cw3, wt1L, wt2L, wt3L);
  conv1_stats<<<2048, 256, 0, stream>>>(x, wt1L, cb1, part1);
  finalize_stats<<<1, 256, 0, stream>>>(part1, g1, bb1, 2048.f * 900.f, stats1);
  conv1_apply_conv2_stats<<<2048, 256, 0, stream>>>(x, wt1L, cb1, stats1,
                                                    wt2L, cb2, part2, p1g);
  finalize_stats<<<1, 256, 0, stream>>>(part2, g2, bb2, 2048.f * 169.f, stats2);
  conv2_apply_conv3_stats<<<2048, 256, 0, stream>>>(p1g, wt2L, cb2, stats2,
                                                    wt3L, cb3, part3, p2g);
  finalize_stats<<<1, 256, 0, stream>>>(part3, g3, bb3, 2048.f * 16.f, stats3);
  conv3_apply<<<256, 256, 0, stream>>>(p2g, wt3L, cb3, stats3, h0g);
  mlp2_kernel<<<64, 256, 0, stream>>>(h0g, traj, eW, eb, oW, ob, out);
  hipMemcpyAsync(out + 409600, score, 4096 * sizeof(float),
                 hipMemcpyDeviceToDevice, stream);
}

// Round 7
// 187.661 us; speedup vs baseline: 2.8549x; 2.8549x over previous
//
#include <hip/hip_runtime.h>
#include <math.h>

typedef unsigned short us;
typedef short s16x8 __attribute__((ext_vector_type(8)));
typedef float f32x4 __attribute__((ext_vector_type(4)));

#define EPSV 1e-5f

static __device__ inline us f2bf(float f) {            // RNE f32->bf16 (finite inputs)
  union { float f; unsigned u; } v; v.f = f;
  unsigned r = v.u + 0x7fffu + ((v.u >> 16) & 1u);
  return (us)(r >> 16);
}

// conv1 A-fragment k->offset table (k = kg*8+j; c=k/9,t=k%9,ki=t/3,kj=t%3;
// off = c*1024+ki*32+kj; k>=27 -> 3072 = zero pad region)
#define SET8(o,a,b,c,d,e,f,g,h) {o[0]=a;o[1]=b;o[2]=c;o[3]=d;o[4]=e;o[5]=f;o[6]=g;o[7]=h;}
static __device__ inline void c1_offsets(int kg, int* offs) {
  switch (kg) {
    case 0: SET8(offs, 0, 1, 2, 32, 33, 34, 64, 65); break;
    case 1: SET8(offs, 66, 1024, 1025, 1026, 1056, 1057, 1058, 1088); break;
    case 2: SET8(offs, 1089, 1090, 2048, 2049, 2050, 2080, 2081, 2082); break;
    default: SET8(offs, 2112, 2113, 2114, 3072, 3072, 3072, 3072, 3072); break;
  }
}

union AU { s16x8 v; us e[8]; };

// ---------------------------------------------------------------- K0: preconvert conv weights
__global__ __launch_bounds__(256) void prep_weights(
    const float* __restrict__ w1, const float* __restrict__ w2,
    const float* __restrict__ w3, us* __restrict__ wt1L,
    us* __restrict__ wt2L, us* __restrict__ wt3L) {
  const int tid = blockIdx.x * 256 + threadIdx.x;
  if (tid < 1280) {
    const int oc = tid / 40, k = tid % 40;
    wt1L[tid] = (k < 27) ? f2bf(w1[oc * 27 + k]) : (us)0;
  }
  for (int i = tid; i < 11520; i += gridDim.x * 256) {
    const int row = i / 40, col = i % 40;
    const int tap = row >> 5, oc = row & 31;
    wt2L[i] = (col < 32) ? f2bf(w2[oc * 288 + col * 9 + tap]) : (us)0;
    wt3L[i] = (col < 32) ? f2bf(w3[oc * 288 + col * 9 + tap]) : (us)0;
  }
}

// ---------------------------------------------------------------- finalize: partials[ch][2048] -> {scale, shift}; 32 blocks = 32 channels
__global__ __launch_bounds__(256) void finalize_stats(
    const float* __restrict__ part, const float* __restrict__ g,
    const float* __restrict__ bb, float cnt, float* __restrict__ stats) {
  __shared__ float redS[256], redQ[256];
  const int ch = blockIdx.x, tid = threadIdx.x;
  const float* ps = part + (size_t)ch * 2048;
  const float* pq = part + (size_t)(32 + ch) * 2048;
  float s = 0.f, q = 0.f;
  for (int i = tid; i < 2048; i += 256) { s += ps[i]; q += pq[i]; }
  redS[tid] = s; redQ[tid] = q;
  __syncthreads();
  for (int off = 128; off; off >>= 1) {
    if (tid < off) { redS[tid] += redS[tid + off]; redQ[tid] += redQ[tid + off]; }
    __syncthreads();
  }
  if (tid == 0) {
    const float mean = redS[0] / cnt;
    const float var = redQ[0] / cnt - mean * mean;
    const float sc = g[ch] * rsqrtf(var + EPSV);
    stats[ch] = sc;
    stats[32 + ch] = bb[ch] - mean * sc;
  }
}

// ---------------------------------------------------------------- K1: conv1 stats only
__global__ __launch_bounds__(256) void conv1_stats(
    const float* __restrict__ x, const us* __restrict__ wt1L,
    const float* __restrict__ cb, float* __restrict__ part1) {
  __shared__ __align__(16) us xsb[4096];      // [3][32][32] bf16 + zero pad
  __shared__ __align__(16) us wt1[1280];      // [32][40]
  __shared__ float csum[32], css[32];
  const int n = blockIdx.x, tid = threadIdx.x;
  const int wave = tid >> 6, lane = tid & 63, row16 = lane & 15, kg = lane >> 4;
  const float4* xp = (const float4*)(x + (size_t)n * 3072);
  for (int i = tid; i < 768; i += 256) {
    const float4 v = xp[i];
    const unsigned lo = f2bf(v.x) | ((unsigned)f2bf(v.y) << 16);
    const unsigned hi = f2bf(v.z) | ((unsigned)f2bf(v.w) << 16);
    *(uint2*)&xsb[i * 4] = make_uint2(lo, hi);
  }
  if (tid < 256) *(uint2*)&xsb[3072 + tid * 4] = make_uint2(0, 0);
  if (tid < 160) ((uint4*)wt1)[tid] = ((const uint4*)wt1L)[tid];
  if (tid < 32) { csum[tid] = 0.f; css[tid] = 0.f; }
  __syncthreads();
  int offs[8]; c1_offsets(kg, offs);
  const s16x8 bf0 = *(const s16x8*)&wt1[row16 * 40 + kg * 8];
  const s16x8 bf1 = *(const s16x8*)&wt1[(16 + row16) * 40 + kg * 8];
  const float bias0 = cb[row16], bias1 = cb[16 + row16];
  float s0 = 0.f, ss0 = 0.f, s1 = 0.f, ss1 = 0.f;
  for (int t = wave; t < 60; t += 4) {        // tile = 2 rows x 8 cols
    const int ip = t >> 2, cg = t & 3;
    const int ai = 2 * ip + (row16 >> 3), aj = cg * 8 + (row16 & 7);
    const int base = (aj < 30) ? (ai * 32 + aj) : 0;
    AU a;
#pragma unroll
    for (int q = 0; q < 8; ++q) a.e[q] = xsb[base + offs[q]];
    f32x4 acc0 = {bias0, bias0, bias0, bias0};
    f32x4 acc1 = {bias1, bias1, bias1, bias1};
    acc0 = __builtin_amdgcn_mfma_f32_16x16x32_bf16(a.v, bf0, acc0, 0, 0, 0);
    acc1 = __builtin_amdgcn_mfma_f32_16x16x32_bf16(a.v, bf1, acc1, 0, 0, 0);
#pragma unroll
    for (int r = 0; r < 4; ++r) {
      const int jc = cg * 8 + (kg & 1) * 4 + r;
      if (jc < 30) {
        s0 += acc0[r]; ss0 += acc0[r] * acc0[r];
        s1 += acc1[r]; ss1 += acc1[r] * acc1[r];
      }
    }
  }
  s0 += __shfl_down(s0, 32); s0 += __shfl_down(s0, 16);
  ss0 += __shfl_down(ss0, 32); ss0 += __shfl_down(ss0, 16);
  s1 += __shfl_down(s1, 32); s1 += __shfl_down(s1, 16);
  ss1 += __shfl_down(ss1, 32); ss1 += __shfl_down(ss1, 16);
  if (lane < 16) {
    atomicAdd(&csum[row16], s0); atomicAdd(&css[row16], ss0);
    atomicAdd(&csum[16 + row16], s1); atomicAdd(&css[16 + row16], ss1);
  }
  __syncthreads();
  if (tid < 32) {
    part1[tid * 2048 + n] = csum[tid];
    part1[(32 + tid) * 2048 + n] = css[tid];
  }
}

// ---------------------------------------------------------------- K2: conv1 recompute + bn1+relu+pool1 -> p1 (bf16) + conv2 partials
__global__ __launch_bounds__(256) void conv1_apply_conv2_stats(
    const float* __restrict__ x, const us* __restrict__ wt1L,
    const float* __restrict__ cb1, const float* __restrict__ stats1,
    const us* __restrict__ wt2L, const float* __restrict__ cb2,
    float* __restrict__ part2, us* __restrict__ p1g) {
  __shared__ __align__(16) us xsb[4096];
  __shared__ __align__(16) us wt1[1280];
  __shared__ __align__(16) us p1b[9000];      // [225][40]
  __shared__ __align__(16) us wt2[11520];     // [9][32][40]
  __shared__ float scS[32], shS[32], csum[32], css[32];
  const int n = blockIdx.x, tid = threadIdx.x;
  const int wave = tid >> 6, lane = tid & 63, row16 = lane & 15, kg = lane >> 4;
  const float4* xp = (const float4*)(x + (size_t)n * 3072);
  for (int i = tid; i < 768; i += 256) {
    const float4 v = xp[i];
    const unsigned lo = f2bf(v.x) | ((unsigned)f2bf(v.y) << 16);
    const unsigned hi = f2bf(v.z) | ((unsigned)f2bf(v.w) << 16);
    *(uint2*)&xsb[i * 4] = make_uint2(lo, hi);
  }
  if (tid < 256) *(uint2*)&xsb[3072 + tid * 4] = make_uint2(0, 0);
  if (tid < 160) ((uint4*)wt1)[tid] = ((const uint4*)wt1L)[tid];
  for (int i = tid; i < 1440; i += 256) ((uint4*)wt2)[i] = ((const uint4*)wt2L)[i];
  if (tid < 32) {
    scS[tid] = stats1[tid]; shS[tid] = stats1[32 + tid];
    csum[tid] = 0.f; css[tid] = 0.f;
  }
  __syncthreads();
  int offs[8]; c1_offsets(kg, offs);
  {
    const s16x8 bf0 = *(const s16x8*)&wt1[row16 * 40 + kg * 8];
    const s16x8 bf1 = *(const s16x8*)&wt1[(16 + row16) * 40 + kg * 8];
    const float bias0 = cb1[row16], bias1 = cb1[16 + row16];
    const float sc0 = scS[row16], sh0 = shS[row16];
    const float sc1 = scS[16 + row16], sh1 = shS[16 + row16];
    for (int t = wave; t < 60; t += 4) {
      const int ip = t >> 2, cg = t & 3;
      const int ai = 2 * ip + (row16 >> 3), aj = cg * 8 + (row16 & 7);
      const int base = (aj < 30) ? (ai * 32 + aj) : 0;
      AU a;
#pragma unroll
      for (int q = 0; q < 8; ++q) a.e[q] = xsb[base + offs[q]];
      f32x4 acc0 = {bias0, bias0, bias0, bias0};
      f32x4 acc1 = {bias1, bias1, bias1, bias1};
      acc0 = __builtin_amdgcn_mfma_f32_16x16x32_bf16(a.v, bf0, acc0, 0, 0, 0);
      acc1 = __builtin_amdgcn_mfma_f32_16x16x32_bf16(a.v, bf1, acc1, 0, 0, 0);
      float v0[4], v1[4];
#pragma unroll
      for (int r = 0; r < 4; ++r) {
        v0[r] = fmaxf(acc0[r] * sc0 + sh0, 0.f);
        v1[r] = fmaxf(acc1[r] * sc1 + sh1, 0.f);
      }
      const float a01_0 = v0[0] + v0[1], a23_0 = v0[2] + v0[3];
      const float a01_1 = v1[0] + v1[1], a23_1 = v1[2] + v1[3];
      const float p01_0 = __shfl_xor(a01_0, 32), p23_0 = __shfl_xor(a23_0, 32);
      const float p01_1 = __shfl_xor(a01_1, 32), p23_1 = __shfl_xor(a23_1, 32);
      if (kg < 2) {                           // rows 2ip (this) + 2ip+1 (partner)
        const int cpa = kg * 2;
        const int oa = ip * 15 + cg * 4 + cpa;
        p1b[oa * 40 + row16] = f2bf((a01_0 + p01_0) * 0.25f);
        p1b[oa * 40 + 16 + row16] = f2bf((a01_1 + p01_1) * 0.25f);
        if (cg < 3 || kg == 0) {              // cpb=3 at cg=3 is out of range
          const int ob = oa + 1;
          p1b[ob * 40 + row16] = f2bf((a23_0 + p23_0) * 0.25f);
          p1b[ob * 40 + 16 + row16] = f2bf((a23_1 + p23_1) * 0.25f);
        }
      }
    }
  }
  __syncthreads();
  // write p1 (bf16) coalesced
  for (int i = tid; i < 900; i += 256) {
    const uint4 v = *(const uint4*)&p1b[(i >> 2) * 40 + (i & 3) * 8];
    *(uint4*)(p1g + (size_t)n * 7200 + i * 8) = v;
  }
  // conv2 stats from LDS p1
  int inb[3];
#pragma unroll
  for (int m = 0; m < 3; ++m) {
    int pixA = (wave + 4 * m) * 16 + row16;
    if (pixA >= 169) pixA = 0;
    const int oi = pixA / 13, oj = pixA - 13 * oi;
    inb[m] = oi * 15 + oj;
  }
  const float b20 = cb2[row16], b21 = cb2[16 + row16];
  f32x4 acc[3][2];
#pragma unroll
  for (int m = 0; m < 3; ++m) {
    acc[m][0] = {b20, b20, b20, b20};
    acc[m][1] = {b21, b21, b21, b21};
  }
#pragma unroll
  for (int tap = 0; tap < 9; ++tap) {
    const int ki = tap / 3, kj = tap % 3;
    const s16x8 bf0 = *(const s16x8*)&wt2[(tap * 32 + row16) * 40 + kg * 8];
    const s16x8 bf1 = *(const s16x8*)&wt2[(tap * 32 + 16 + row16) * 40 + kg * 8];
#pragma unroll
    for (int m = 0; m < 3; ++m) {
      const s16x8 a = *(const s16x8*)&p1b[(inb[m] + ki * 15 + kj) * 40 + kg * 8];
      acc[m][0] = __builtin_amdgcn_mfma_f32_16x16x32_bf16(a, bf0, acc[m][0], 0, 0, 0);
      acc[m][1] = __builtin_amdgcn_mfma_f32_16x16x32_bf16(a, bf1, acc[m][1], 0, 0, 0);
    }
  }
  float s0 = 0.f, ss0 = 0.f, s1 = 0.f, ss1 = 0.f;
#pragma unroll
  for (int m = 0; m < 3; ++m)
#pragma unroll
    for (int r = 0; r < 4; ++r) {
      const int pix = (wave + 4 * m) * 16 + kg * 4 + r;
      if (pix < 169) {
        const float u0 = acc[m][0][r], u1 = acc[m][1][r];
        s0 += u0; ss0 += u0 * u0; s1 += u1; ss1 += u1 * u1;
      }
    }
  s0 += __shfl_down(s0, 32); s0 += __shfl_down(s0, 16);
  ss0 += __shfl_down(ss0, 32); ss0 += __shfl_down(ss0, 16);
  s1 += __shfl_down(s1, 32); s1 += __shfl_down(s1, 16);
  ss1 += __shfl_down(ss1, 32); ss1 += __shfl_down(ss1, 16);
  if (lane < 16) {
    atomicAdd(&csum[row16], s0); atomicAdd(&css[row16], ss0);
    atomicAdd(&csum[16 + row16], s1); atomicAdd(&css[16 + row16], ss1);
  }
  __syncthreads();
  if (tid < 32) {
    part2[tid * 2048 + n] = csum[tid];
    part2[(32 + tid) * 2048 + n] = css[tid];
  }
}

// ---------------------------------------------------------------- K3: conv2 recompute + bn2+relu+pool2 -> p2 (bf16) + conv3 partials
__global__ __launch_bounds__(256) void conv2_apply_conv3_stats(
    const us* __restrict__ p1g, const us* __restrict__ wt2L,
    const float* __restrict__ cb2, const float* __restrict__ stats2,
    const us* __restrict__ wt3L, const float* __restrict__ cb3,
    float* __restrict__ part3, us* __restrict__ p2g) {
  __shared__ __align__(16) us p1b[9000];      // [225][40]
  __shared__ __align__(16) us wt2[11520];
  __shared__ __align__(16) float p2a[1188];   // [36][33] f32 accum
  __shared__ __align__(16) us p2b[1440];      // [36][40]
  __shared__ float scS[32], shS[32], csum[32], css[32];
  const int n = blockIdx.x, tid = threadIdx.x;
  const int wave = tid >> 6, lane = tid & 63, row16 = lane & 15, kg = lane >> 4;
  for (int i = tid; i < 900; i += 256) {
    const uint4 v = *(const uint4*)(p1g + (size_t)n * 7200 + i * 8);
    *(uint4*)&p1b[(i >> 2) * 40 + (i & 3) * 8] = v;
  }
  for (int i = tid; i < 1440; i += 256) ((uint4*)wt2)[i] = ((const uint4*)wt2L)[i];
  for (int i = tid; i < 1188; i += 256) p2a[i] = 0.f;
  if (tid < 32) {
    scS[tid] = stats2[tid]; shS[tid] = stats2[32 + tid];
    csum[tid] = 0.f; css[tid] = 0.f;
  }
  __syncthreads();
  int inb[3];
#pragma unroll
  for (int m = 0; m < 3; ++m) {
    int pixA = (wave + 4 * m) * 16 + row16;
    if (pixA >= 169) pixA = 0;
    const int oi = pixA / 13, oj = pixA - 13 * oi;
    inb[m] = oi * 15 + oj;
  }
  const float b20 = cb2[row16], b21 = cb2[16 + row16];
  f32x4 acc[3][2];
#pragma unroll
  for (int m = 0; m < 3; ++m) {
    acc[m][0] = {b20, b20, b20, b20};
    acc[m][1] = {b21, b21, b21, b21};
  }
#pragma unroll
  for (int tap = 0; tap < 9; ++tap) {
    const int ki = tap / 3, kj = tap % 3;
    const s16x8 bf0 = *(const s16x8*)&wt2[(tap * 32 + row16) * 40 + kg * 8];
    const s16x8 bf1 = *(const s16x8*)&wt2[(tap * 32 + 16 + row16) * 40 + kg * 8];
#pragma unroll
    for (int m = 0; m < 3; ++m) {
      const s16x8 a = *(const s16x8*)&p1b[(inb[m] + ki * 15 + kj) * 40 + kg * 8];
      acc[m][0] = __builtin_amdgcn_mfma_f32_16x16x32_bf16(a, bf0, acc[m][0], 0, 0, 0);
      acc[m][1] = __builtin_amdgcn_mfma_f32_16x16x32_bf16(a, bf1, acc[m][1], 0, 0, 0);
    }
  }
  const float sc0 = scS[row16], sh0 = shS[row16];
  const float sc1 = scS[16 + row16], sh1 = shS[16 + row16];
#pragma unroll
  for (int m = 0; m < 3; ++m)
#pragma unroll
    for (int r = 0; r < 4; ++r) {
      const int pix = (wave + 4 * m) * 16 + kg * 4 + r;
      if (pix < 169) {
        const int i = pix / 13, j = pix - 13 * i;
        if (i < 12 && j < 12) {
          const int op = (i >> 1) * 6 + (j >> 1);
          atomicAdd(&p2a[op * 33 + row16], fmaxf(acc[m][0][r] * sc0 + sh0, 0.f) * 0.25f);
          atomicAdd(&p2a[op * 33 + 16 + row16], fmaxf(acc[m][1][r] * sc1 + sh1, 0.f) * 0.25f);
        }
      }
    }
  __syncthreads();
  if (tid < 144) {
    const int row = tid >> 2, col = (tid & 3) * 8;
    uint4 v;
    us tmp[8];
#pragma unroll
    for (int q = 0; q < 8; ++q) tmp[q] = f2bf(p2a[row * 33 + col + q]);
    v.x = tmp[0] | ((unsigned)tmp[1] << 16); v.y = tmp[2] | ((unsigned)tmp[3] << 16);
    v.z = tmp[4] | ((unsigned)tmp[5] << 16); v.w = tmp[6] | ((unsigned)tmp[7] << 16);
    *(uint4*)&p2b[row * 40 + col] = v;
    *(uint4*)(p2g + (size_t)n * 1152 + tid * 8) = v;
  }
  __syncthreads();
  if (wave < 2) {                              // conv3 stats (16 out px, 1 m-tile)
    const int ocb = wave * 16;
    const int inb3 = (row16 >> 2) * 6 + (row16 & 3);
    const float b3 = cb3[ocb + row16];
    f32x4 a3 = {b3, b3, b3, b3};
#pragma unroll
    for (int tap = 0; tap < 9; ++tap) {
      const int ki = tap / 3, kj = tap % 3;
      const s16x8 bf = *(const s16x8*)&wt3L[(tap * 32 + ocb + row16) * 40 + kg * 8];
      const s16x8 a = *(const s16x8*)&p2b[(inb3 + ki * 6 + kj) * 40 + kg * 8];
      a3 = __builtin_amdgcn_mfma_f32_16x16x32_bf16(a, bf, a3, 0, 0, 0);
    }
    float s = a3[0] + a3[1] + a3[2] + a3[3];
    float ss = a3[0]*a3[0] + a3[1]*a3[1] + a3[2]*a3[2] + a3[3]*a3[3];
    s += __shfl_down(s, 32); s += __shfl_down(s, 16);
    ss += __shfl_down(ss, 32); ss += __shfl_down(ss, 16);
    if (lane < 16) { atomicAdd(&csum[ocb + row16], s); atomicAdd(&css[ocb + row16], ss); }
  }
  __syncthreads();
  if (tid < 32) {
    part3[tid * 2048 + n] = csum[tid];
    part3[(32 + tid) * 2048 + n] = css[tid];
  }
}

// ---------------------------------------------------------------- K4: conv3 recompute + bn3+relu+pool3 -> h0 (8 samples/block)
__global__ __launch_bounds__(256) void conv3_apply(
    const us* __restrict__ p2g, const us* __restrict__ wt3L,
    const float* __restrict__ cb3, const float* __restrict__ stats3,
    float* __restrict__ h0g) {
  __shared__ __align__(16) us p2L[11520];      // [8][36][40]
  __shared__ __align__(16) us wt3[11520];
  __shared__ float scS[32], shS[32];
  __shared__ float h0a[1024];
  const int n0 = blockIdx.x * 8, tid = threadIdx.x;
  const int wave = tid >> 6, lane = tid & 63, row16 = lane & 15, kg = lane >> 4;
  for (int i = tid; i < 1152; i += 256) {
    const int s = i / 144, ci = i - s * 144;
    const uint4 v = *(const uint4*)(p2g + (size_t)n0 * 1152 + i * 8);
    *(uint4*)&p2L[(s * 36 + (ci >> 2)) * 40 + (ci & 3) * 8] = v;
  }
  for (int i = tid; i < 1440; i += 256) ((uint4*)wt3)[i] = ((const uint4*)wt3L)[i];
  for (int i = tid; i < 1024; i += 256) h0a[i] = 0.f;
  if (tid < 32) { scS[tid] = stats3[tid]; shS[tid] = stats3[32 + tid]; }
  __syncthreads();
  const int inb3 = (row16 >> 2) * 6 + (row16 & 3);
  const float b30 = cb3[row16], b31 = cb3[16 + row16];
  f32x4 accA[2][2];
#pragma unroll
  for (int si = 0; si < 2; ++si) {
    accA[si][0] = {b30, b30, b30, b30};
    accA[si][1] = {b31, b31, b31, b31};
  }
#pragma unroll
  for (int tap = 0; tap < 9; ++tap) {
    const int ki = tap / 3, kj = tap % 3;
    const s16x8 bf0 = *(const s16x8*)&wt3[(tap * 32 + row16) * 40 + kg * 8];
    const s16x8 bf1 = *(const s16x8*)&wt3[(tap * 32 + 16 + row16) * 40 + kg * 8];
#pragma unroll
    for (int si = 0; si < 2; ++si) {
      const int s = wave + 4 * si;
      const s16x8 a = *(const s16x8*)&p2L[(s * 36 + inb3 + ki * 6 + kj) * 40 + kg * 8];
      accA[si][0] = __builtin_amdgcn_mfma_f32_16x16x32_bf16(a, bf0, accA[si][0], 0, 0, 0);
      accA[si][1] = __builtin_amdgcn_mfma_f32_16x16x32_bf16(a, bf1, accA[si][1], 0, 0, 0);
    }
  }
  const float sc0 = scS[row16], sh0 = shS[row16];
  const float sc1 = scS[16 + row16], sh1 = shS[16 + row16];
#pragma unroll
  for (int si = 0; si < 2; ++si) {
    const int s = wave + 4 * si;
#pragma unroll
    for (int r = 0; r < 4; ++r) {
      const int pix = kg * 4 + r;
      const int op = ((pix >> 2) >> 1) * 2 + ((pix & 3) >> 1);
      atomicAdd(&h0a[s * 128 + row16 * 4 + op], fmaxf(accA[si][0][r] * sc0 + sh0, 0.f) * 0.25f);
      atomicAdd(&h0a[s * 128 + (16 + row16) * 4 + op], fmaxf(accA[si][1][r] * sc1 + sh1, 0.f) * 0.25f);
    }
  }
  __syncthreads();
  ((float4*)(h0g + (size_t)n0 * 128))[tid] = ((const float4*)h0a)[tid];
}

// ---------------------------------------------------------------- K5: MFMA routed MLP
#define STR 136
__global__ __launch_bounds__(256) void mlp2_kernel(
    const float* __restrict__ h0, const float* __restrict__ traj,
    const float* __restrict__ eW, const float* __restrict__ eb,
    const float* __restrict__ oW, const float* __restrict__ ob,
    float* __restrict__ out) {
  __shared__ __align__(16) us wexp[3 * 128 * STR];
  __shared__ __align__(16) us owl[112 * STR];
  __shared__ __align__(16) us htile[4][16 * STR];
  __shared__ float ebl[384];
  __shared__ float obl[112];
  const int tid = threadIdx.x, wave = tid >> 6, lane = tid & 63;
  const int row16 = lane & 15, kg = lane >> 4;
  const int rbase = blockIdx.x * 64 + wave * 16;
  for (int i = tid; i < 12288; i += 256) {
    const int e = i >> 12, rem = i & 4095, o = rem >> 5, d4 = (rem & 31) * 4;
    const float4 v = *(const float4*)(eW + ((e * 128 + o) * 128 + d4));
    const unsigned lo = f2bf(v.x) | ((unsigned)f2bf(v.y) << 16);
    const unsigned hi = f2bf(v.z) | ((unsigned)f2bf(v.w) << 16);
    *(uint2*)&wexp[(e * 128 + o) * STR + d4] = make_uint2(lo, hi);
  }
  for (int i = tid; i < 112 * 32; i += 256) {
    const int cls = i >> 5, d4 = (i & 31) * 4;
    float4 v = make_float4(0.f, 0.f, 0.f, 0.f);
    if (cls < 100) v = *(const float4*)(oW + cls * 128 + d4);
    const unsigned lo = f2bf(v.x) | ((unsigned)f2bf(v.y) << 16);
    const unsigned hi = f2bf(v.z) | ((unsigned)f2bf(v.w) << 16);
    *(uint2*)&owl[cls * STR + d4] = make_uint2(lo, hi);
  }
  for (int i = tid; i < 384; i += 256) ebl[i] = eb[i];
  if (tid < 112) obl[tid] = (tid < 100) ? ob[tid] : 0.f;
  us* ht = &htile[wave][0];
  for (int i = lane; i < 256; i += 64) {
    const int row = i >> 4, d8 = (i & 15) * 8;
    const int rowg = rbase + row;
    const float4 v0 = *(const float4*)(h0 + (size_t)(rowg >> 1) * 128 + d8);
    const float4 v1 = *(const float4*)(h0 + (size_t)(rowg >> 1) * 128 + d8 + 4);
    uint4 p;
    p.x = f2bf(v0.x) | ((unsigned)f2bf(v0.y) << 16);
    p.y = f2bf(v0.z) | ((unsigned)f2bf(v0.w) << 16);
    p.z = f2bf(v1.x) | ((unsigned)f2bf(v1.y) << 16);
    p.w = f2bf(v1.z) | ((unsigned)f2bf(v1.w) << 16);
    *(uint4*)&ht[row * STR + d8] = p;
  }
  __syncthreads();
  float accv[8][4];
#pragma unroll
  for (int ct = 0; ct < 8; ++ct)
#pragma unroll
    for (int r = 0; r < 4; ++r) {
      const int rowg = rbase + kg * 4 + r;
      accv[ct][r] = h0[(size_t)(rowg >> 1) * 128 + ct * 16 + row16];
    }
  for (int d = 0; d < 3; ++d) {
    int sel[4];
#pragma unroll
    for (int r = 0; r < 4; ++r) {
      const int rowg = rbase + kg * 4 + r;
      const float4 t4 = *(const float4*)(traj + d * 16384 + rowg * 4);
      int s = 0; float mx = t4.x;
      if (t4.y > mx) { mx = t4.y; s = 1; }
      if (t4.z > mx) { mx = t4.z; s = 2; }
      if (t4.w > mx) { mx = t4.w; s = 3; }
      sel[r] = s;
    }
    s16x8 a[4];
#pragma unroll
    for (int kc = 0; kc < 4; ++kc)
      a[kc] = *(const s16x8*)&ht[row16 * STR + kc * 32 + kg * 8];
    float newacc[8][4];
#pragma unroll
    for (int ct = 0; ct < 8; ++ct)
#pragma unroll
      for (int r = 0; r < 4; ++r)
        newacc[ct][r] = (sel[r] == 3) ? accv[ct][r] : 0.f;
#pragma unroll
    for (int e = 0; e < 3; ++e) {
#pragma unroll
      for (int ct = 0; ct < 8; ++ct) {
        f32x4 t = {0.f, 0.f, 0.f, 0.f};
#pragma unroll
        for (int kc = 0; kc < 4; ++kc) {
          const s16x8 b = *(const s16x8*)&wexp[(e * 128 + ct * 16 + row16) * STR + kc * 32 + kg * 8];
          t = __builtin_amdgcn_mfma_f32_16x16x32_bf16(a[kc], b, t, 0, 0, 0);
        }
        const float bias = ebl[e * 128 + ct * 16 + row16];
#pragma unroll
        for (int r = 0; r < 4; ++r)
          if (sel[r] == e) newacc[ct][r] = t[r] + bias;
      }
    }
#pragma unroll
    for (int ct = 0; ct < 8; ++ct)
#pragma unroll
      for (int r = 0; r < 4; ++r) {
        float v = newacc[ct][r];
        if (d < 2) v = fmaxf(v, 0.f);
        accv[ct][r] = v;
        ht[(kg * 4 + r) * STR + ct * 16 + row16] = f2bf(v);
      }
  }
  s16x8 a[4];
#pragma unroll
  for (int kc = 0; kc < 4; ++kc)
    a[kc] = *(const s16x8*)&ht[row16 * STR + kc * 32 + kg * 8];
  float preds[7][4];
#pragma unroll
  for (int ct = 0; ct < 7; ++ct) {
    f32x4 t = {0.f, 0.f, 0.f, 0.f};
#pragma unroll
    for (int kc = 0; kc < 4; ++kc) {
      const s16x8 b = *(const s16x8*)&owl[(ct * 16 + row16) * STR + kc * 32 + kg * 8];
      t = __builtin_amdgcn_mfma_f32_16x16x32_bf16(a[kc], b, t, 0, 0, 0);
    }
    const float bias = obl[ct * 16 + row16];
#pragma unroll
    for (int r = 0; r < 4; ++r) preds[ct][r] = t[r] + bias;
  }
  const bool v6 = (96 + row16) < 100;
#pragma unroll
  for (int r = 0; r < 4; ++r) {
    float mx = -INFINITY;
#pragma unroll
    for (int ct = 0; ct < 7; ++ct)
      if (ct < 6 || v6) mx = fmaxf(mx, preds[ct][r]);
    mx = fmaxf(mx, __shfl_xor(mx, 1)); mx = fmaxf(mx, __shfl_xor(mx, 2));
    mx = fmaxf(mx, __shfl_xor(mx, 4)); mx = fmaxf(mx, __shfl_xor(mx, 8));
    float s = 0.f;
#pragma unroll
    for (int ct = 0; ct < 7; ++ct)
      if (ct < 6 || v6) s += expf(preds[ct][r] - mx);
    s += __shfl_xor(s, 1); s += __shfl_xor(s, 2);
    s += __shfl_xor(s, 4); s += __shfl_xor(s, 8);
    const float lg = mx + logf(s);
    const int rowg = rbase + kg * 4 + r;
#pragma unroll
    for (int ct = 0; ct < 7; ++ct)
      if (ct < 6 || v6) out[(size_t)rowg * 100 + ct * 16 + row16] = preds[ct][r] - lg;
  }
}

// ---------------------------------------------------------------- launch
extern "C" void kernel_launch(void* const* d_in, const int* in_sizes, int n_in,
                              void* d_out, int out_size, void* d_ws, size_t ws_size,
                              hipStream_t stream) {
  const float* x     = (const float*)d_in[0];
  const float* traj  = (const float*)d_in[1];
  const float* score = (const float*)d_in[2];
  const float* cw1 = (const float*)d_in[3];
  const float* cb1 = (const float*)d_in[4];
  const float* g1  = (const float*)d_in[5];
  const float* bb1 = (const float*)d_in[6];
  const float* cw2 = (const float*)d_in[7];
  const float* cb2 = (const float*)d_in[8];
  const float* g2  = (const float*)d_in[9];
  const float* bb2 = (const float*)d_in[10];
  const float* cw3 = (const float*)d_in[11];
  const float* cb3 = (const float*)d_in[12];
  const float* g3  = (const float*)d_in[13];
  const float* bb3 = (const float*)d_in[14];
  const float* eW  = (const float*)d_in[15];
  const float* eb  = (const float*)d_in[16];
  const float* oW  = (const float*)d_in[17];
  const float* ob  = (const float*)d_in[18];
  float* out = (float*)d_out;

  char* ws = (char*)d_ws;
  float* stats1 = (float*)ws;                    // 64 f32 {sc,sh}
  float* stats2 = (float*)(ws + 256);
  float* stats3 = (float*)(ws + 512);
  us* wt1L = (us*)(ws + 1024);                   // 1280 us
  us* wt2L = (us*)(ws + 4096);                   // 11520 us = 23040 B
  us* wt3L = (us*)(ws + 4096 + 23040);           // 11520 us
  us* p1g  = (us*)(ws + 65536);                  // bf16 [2048][225][32] = 29,491,200 B
  us* p2g  = (us*)(ws + 65536 + 29491200);       // bf16 [2048][36][32]  =  4,718,592 B
  float* h0g = (float*)(ws + 65536 + 29491200 + 4718592);  // f32 [2048][128] = 1 MB
  char* pbase = ws + 65536 + 29491200 + 4718592 + 1048576;
  float* part1 = (float*)pbase;                  // [64][2048] f32 = 512 KB
  float* part2 = (float*)(pbase + 524288);
  float* part3 = (float*)(pbase + 1048576);

  prep_weights<<<12, 256, 0, stream>>>(cw1, cw2, cw3, wt1L, wt2L, wt3L);
  conv1_stats<<<2048, 256, 0, stream>>>(x, wt1L, cb1, part1);
  finalize_stats<<<32, 256, 0, stream>>>(part1, g1, bb1, 2048.f * 900.f, stats1);
  conv1_apply_conv2_stats<<<2048, 256, 0, stream>>>(x, wt1L, cb1, stats1,
                                                    wt2L, cb2, part2, p1g);
  finalize_stats<<<32, 256, 0, stream>>>(part2, g2, bb2, 2048.f * 169.f, stats2);
  conv2_apply_conv3_stats<<<2048, 256, 0, stream>>>(p1g, wt2L, cb2, stats2,
                                                    wt3L, cb3, part3, p2g);
  finalize_stats<<<32, 256, 0, stream>>>(part3, g3, bb3, 2048.f * 16.f, stats3);
  conv3_apply<<<256, 256, 0, stream>>>(p2g, wt3L, cb3, stats3, h0g);
  mlp2_kernel<<<64, 256, 0, stream>>>(h0g, traj, eW, eb, oW, ob, out);
  hipMemcpyAsync(out + 409600, score, 4096 * sizeof(float),
                 hipMemcpyDeviceToDevice, stream);
}

// Round 8
// 142.934 us; speedup vs baseline: 3.7483x; 1.3129x over previous
//
#include <hip/hip_runtime.h>
#include <math.h>

typedef unsigned short us;
typedef short s16x8 __attribute__((ext_vector_type(8)));
typedef float f32x4 __attribute__((ext_vector_type(4)));

#define EPSV 1e-5f

static __device__ inline us f2bf(float f) {            // RNE f32->bf16 (finite inputs)
  union { float f; unsigned u; } v; v.f = f;
  unsigned r = v.u + 0x7fffu + ((v.u >> 16) & 1u);
  return (us)(r >> 16);
}

// conv1 A-fragment k->offset table
#define SET8(o,a,b,c,d,e,f,g,h) {o[0]=a;o[1]=b;o[2]=c;o[3]=d;o[4]=e;o[5]=f;o[6]=g;o[7]=h;}
static __device__ inline void c1_offsets(int kg, int* offs) {
  switch (kg) {
    case 0: SET8(offs, 0, 1, 2, 32, 33, 34, 64, 65); break;
    case 1: SET8(offs, 66, 1024, 1025, 1026, 1056, 1057, 1058, 1088); break;
    case 2: SET8(offs, 1089, 1090, 2048, 2049, 2050, 2080, 2081, 2082); break;
    default: SET8(offs, 2112, 2113, 2114, 3072, 3072, 3072, 3072, 3072); break;
  }
}

union AU { s16x8 v; us e[8]; };

// ---------------------------------------------------------------- K0: preconvert conv weights
__global__ __launch_bounds__(256) void prep_weights(
    const float* __restrict__ w1, const float* __restrict__ w2,
    const float* __restrict__ w3, us* __restrict__ wt1L,
    us* __restrict__ wt2L, us* __restrict__ wt3L) {
  const int tid = blockIdx.x * 256 + threadIdx.x;
  if (tid < 1280) {
    const int oc = tid / 40, k = tid % 40;
    wt1L[tid] = (k < 27) ? f2bf(w1[oc * 27 + k]) : (us)0;
  }
  for (int i = tid; i < 11520; i += gridDim.x * 256) {
    const int row = i / 40, col = i % 40;
    const int tap = row >> 5, oc = row & 31;
    wt2L[i] = (col < 32) ? f2bf(w2[oc * 288 + col * 9 + tap]) : (us)0;
    wt3L[i] = (col < 32) ? f2bf(w3[oc * 288 + col * 9 + tap]) : (us)0;
  }
}

// ---------------------------------------------------------------- finalize: partials[ch][2048] -> {scale, shift}
__global__ __launch_bounds__(256) void finalize_stats(
    const float* __restrict__ part, const float* __restrict__ g,
    const float* __restrict__ bb, float cnt, float* __restrict__ stats) {
  __shared__ float redS[256], redQ[256];
  const int ch = blockIdx.x, tid = threadIdx.x;
  const float* ps = part + (size_t)ch * 2048;
  const float* pq = part + (size_t)(32 + ch) * 2048;
  float s = 0.f, q = 0.f;
  for (int i = tid; i < 2048; i += 256) { s += ps[i]; q += pq[i]; }
  redS[tid] = s; redQ[tid] = q;
  __syncthreads();
  for (int off = 128; off; off >>= 1) {
    if (tid < off) { redS[tid] += redS[tid + off]; redQ[tid] += redQ[tid + off]; }
    __syncthreads();
  }
  if (tid == 0) {
    const float mean = redS[0] / cnt;
    const float var = redQ[0] / cnt - mean * mean;
    const float sc = g[ch] * rsqrtf(var + EPSV);
    stats[ch] = sc;
    stats[32 + ch] = bb[ch] - mean * sc;
  }
}

// ---------------------------------------------------------------- K1: conv1 stats only
__global__ __launch_bounds__(256) void conv1_stats(
    const float* __restrict__ x, const us* __restrict__ wt1L,
    const float* __restrict__ cb, float* __restrict__ part1) {
  __shared__ __align__(16) us xsb[4096];
  __shared__ __align__(16) us wt1[1280];
  __shared__ float csum[32], css[32];
  const int n = blockIdx.x, tid = threadIdx.x;
  const int wave = tid >> 6, lane = tid & 63, row16 = lane & 15, kg = lane >> 4;
  const float4* xp = (const float4*)(x + (size_t)n * 3072);
  for (int i = tid; i < 768; i += 256) {
    const float4 v = xp[i];
    const unsigned lo = f2bf(v.x) | ((unsigned)f2bf(v.y) << 16);
    const unsigned hi = f2bf(v.z) | ((unsigned)f2bf(v.w) << 16);
    *(uint2*)&xsb[i * 4] = make_uint2(lo, hi);
  }
  if (tid < 256) *(uint2*)&xsb[3072 + tid * 4] = make_uint2(0, 0);
  if (tid < 160) ((uint4*)wt1)[tid] = ((const uint4*)wt1L)[tid];
  if (tid < 32) { csum[tid] = 0.f; css[tid] = 0.f; }
  __syncthreads();
  int offs[8]; c1_offsets(kg, offs);
  const s16x8 bf0 = *(const s16x8*)&wt1[row16 * 40 + kg * 8];
  const s16x8 bf1 = *(const s16x8*)&wt1[(16 + row16) * 40 + kg * 8];
  const float bias0 = cb[row16], bias1 = cb[16 + row16];
  float s0 = 0.f, ss0 = 0.f, s1 = 0.f, ss1 = 0.f;
  for (int t = wave; t < 60; t += 4) {        // tile = 2 rows x 8 cols
    const int ip = t >> 2, cg = t & 3;
    const int ai = 2 * ip + (row16 >> 3), aj = cg * 8 + (row16 & 7);
    const int base = (aj < 30) ? (ai * 32 + aj) : 0;
    AU a;
#pragma unroll
    for (int q = 0; q < 8; ++q) a.e[q] = xsb[base + offs[q]];
    f32x4 acc0 = {bias0, bias0, bias0, bias0};
    f32x4 acc1 = {bias1, bias1, bias1, bias1};
    acc0 = __builtin_amdgcn_mfma_f32_16x16x32_bf16(a.v, bf0, acc0, 0, 0, 0);
    acc1 = __builtin_amdgcn_mfma_f32_16x16x32_bf16(a.v, bf1, acc1, 0, 0, 0);
#pragma unroll
    for (int r = 0; r < 4; ++r) {
      const int jc = cg * 8 + (kg & 1) * 4 + r;
      if (jc < 30) {
        s0 += acc0[r]; ss0 += acc0[r] * acc0[r];
        s1 += acc1[r]; ss1 += acc1[r] * acc1[r];
      }
    }
  }
  s0 += __shfl_down(s0, 32); s0 += __shfl_down(s0, 16);
  ss0 += __shfl_down(ss0, 32); ss0 += __shfl_down(ss0, 16);
  s1 += __shfl_down(s1, 32); s1 += __shfl_down(s1, 16);
  ss1 += __shfl_down(ss1, 32); ss1 += __shfl_down(ss1, 16);
  if (lane < 16) {
    atomicAdd(&csum[row16], s0); atomicAdd(&css[row16], ss0);
    atomicAdd(&csum[16 + row16], s1); atomicAdd(&css[16 + row16], ss1);
  }
  __syncthreads();
  if (tid < 32) {
    part1[tid * 2048 + n] = csum[tid];
    part1[(32 + tid) * 2048 + n] = css[tid];
  }
}

// ---------------------------------------------------------------- K2: conv1 recompute + bn1+relu+pool1 -> p1 (bf16) + conv2 partials
__global__ __launch_bounds__(256) void conv1_apply_conv2_stats(
    const float* __restrict__ x, const us* __restrict__ wt1L,
    const float* __restrict__ cb1, const float* __restrict__ stats1,
    const us* __restrict__ wt2L, const float* __restrict__ cb2,
    float* __restrict__ part2, us* __restrict__ p1g) {
  __shared__ __align__(16) us xsb[4096];
  __shared__ __align__(16) us wt1[1280];
  __shared__ __align__(16) us p1b[9000];      // [225][40]
  __shared__ __align__(16) us wt2[11520];     // [9][32][40]
  __shared__ float scS[32], shS[32], csum[32], css[32];
  const int n = blockIdx.x, tid = threadIdx.x;
  const int wave = tid >> 6, lane = tid & 63, row16 = lane & 15, kg = lane >> 4;
  const float4* xp = (const float4*)(x + (size_t)n * 3072);
  for (int i = tid; i < 768; i += 256) {
    const float4 v = xp[i];
    const unsigned lo = f2bf(v.x) | ((unsigned)f2bf(v.y) << 16);
    const unsigned hi = f2bf(v.z) | ((unsigned)f2bf(v.w) << 16);
    *(uint2*)&xsb[i * 4] = make_uint2(lo, hi);
  }
  if (tid < 256) *(uint2*)&xsb[3072 + tid * 4] = make_uint2(0, 0);
  if (tid < 160) ((uint4*)wt1)[tid] = ((const uint4*)wt1L)[tid];
  for (int i = tid; i < 1440; i += 256) ((uint4*)wt2)[i] = ((const uint4*)wt2L)[i];
  if (tid < 32) {
    scS[tid] = stats1[tid]; shS[tid] = stats1[32 + tid];
    csum[tid] = 0.f; css[tid] = 0.f;
  }
  __syncthreads();
  int offs[8]; c1_offsets(kg, offs);
  {
    const s16x8 bf0 = *(const s16x8*)&wt1[row16 * 40 + kg * 8];
    const s16x8 bf1 = *(const s16x8*)&wt1[(16 + row16) * 40 + kg * 8];
    const float bias0 = cb1[row16], bias1 = cb1[16 + row16];
    const float sc0 = scS[row16], sh0 = shS[row16];
    const float sc1 = scS[16 + row16], sh1 = shS[16 + row16];
    for (int t = wave; t < 60; t += 4) {
      const int ip = t >> 2, cg = t & 3;
      const int ai = 2 * ip + (row16 >> 3), aj = cg * 8 + (row16 & 7);
      const int base = (aj < 30) ? (ai * 32 + aj) : 0;
      AU a;
#pragma unroll
      for (int q = 0; q < 8; ++q) a.e[q] = xsb[base + offs[q]];
      f32x4 acc0 = {bias0, bias0, bias0, bias0};
      f32x4 acc1 = {bias1, bias1, bias1, bias1};
      acc0 = __builtin_amdgcn_mfma_f32_16x16x32_bf16(a.v, bf0, acc0, 0, 0, 0);
      acc1 = __builtin_amdgcn_mfma_f32_16x16x32_bf16(a.v, bf1, acc1, 0, 0, 0);
      float v0[4], v1[4];
#pragma unroll
      for (int r = 0; r < 4; ++r) {
        v0[r] = fmaxf(acc0[r] * sc0 + sh0, 0.f);
        v1[r] = fmaxf(acc1[r] * sc1 + sh1, 0.f);
      }
      const float a01_0 = v0[0] + v0[1], a23_0 = v0[2] + v0[3];
      const float a01_1 = v1[0] + v1[1], a23_1 = v1[2] + v1[3];
      const float p01_0 = __shfl_xor(a01_0, 32), p23_0 = __shfl_xor(a23_0, 32);
      const float p01_1 = __shfl_xor(a01_1, 32), p23_1 = __shfl_xor(a23_1, 32);
      if (kg < 2) {                           // rows 2ip (this) + 2ip+1 (partner)
        const int cpa = kg * 2;
        const int oa = ip * 15 + cg * 4 + cpa;
        p1b[oa * 40 + row16] = f2bf((a01_0 + p01_0) * 0.25f);
        p1b[oa * 40 + 16 + row16] = f2bf((a01_1 + p01_1) * 0.25f);
        if (cg < 3 || kg == 0) {
          const int ob = oa + 1;
          p1b[ob * 40 + row16] = f2bf((a23_0 + p23_0) * 0.25f);
          p1b[ob * 40 + 16 + row16] = f2bf((a23_1 + p23_1) * 0.25f);
        }
      }
    }
  }
  __syncthreads();
  // write p1 (bf16) coalesced
  for (int i = tid; i < 900; i += 256) {
    const uint4 v = *(const uint4*)&p1b[(i >> 2) * 40 + (i & 3) * 8];
    *(uint4*)(p1g + (size_t)n * 7200 + i * 8) = v;
  }
  // conv2 stats from LDS p1 (full 169 raster)
  int inb[3];
#pragma unroll
  for (int m = 0; m < 3; ++m) {
    int pixA = (wave + 4 * m) * 16 + row16;
    if (pixA >= 169) pixA = 0;
    const int oi = pixA / 13, oj = pixA - 13 * oi;
    inb[m] = oi * 15 + oj;
  }
  const float b20 = cb2[row16], b21 = cb2[16 + row16];
  f32x4 acc[3][2];
#pragma unroll
  for (int m = 0; m < 3; ++m) {
    acc[m][0] = {b20, b20, b20, b20};
    acc[m][1] = {b21, b21, b21, b21};
  }
#pragma unroll
  for (int tap = 0; tap < 9; ++tap) {
    const int ki = tap / 3, kj = tap % 3;
    const s16x8 bf0 = *(const s16x8*)&wt2[(tap * 32 + row16) * 40 + kg * 8];
    const s16x8 bf1 = *(const s16x8*)&wt2[(tap * 32 + 16 + row16) * 40 + kg * 8];
#pragma unroll
    for (int m = 0; m < 3; ++m) {
      const s16x8 a = *(const s16x8*)&p1b[(inb[m] + ki * 15 + kj) * 40 + kg * 8];
      acc[m][0] = __builtin_amdgcn_mfma_f32_16x16x32_bf16(a, bf0, acc[m][0], 0, 0, 0);
      acc[m][1] = __builtin_amdgcn_mfma_f32_16x16x32_bf16(a, bf1, acc[m][1], 0, 0, 0);
    }
  }
  float s0 = 0.f, ss0 = 0.f, s1 = 0.f, ss1 = 0.f;
#pragma unroll
  for (int m = 0; m < 3; ++m)
#pragma unroll
    for (int r = 0; r < 4; ++r) {
      const int pix = (wave + 4 * m) * 16 + kg * 4 + r;
      if (pix < 169) {
        const float u0 = acc[m][0][r], u1 = acc[m][1][r];
        s0 += u0; ss0 += u0 * u0; s1 += u1; ss1 += u1 * u1;
      }
    }
  s0 += __shfl_down(s0, 32); s0 += __shfl_down(s0, 16);
  ss0 += __shfl_down(ss0, 32); ss0 += __shfl_down(ss0, 16);
  s1 += __shfl_down(s1, 32); s1 += __shfl_down(s1, 16);
  ss1 += __shfl_down(ss1, 32); ss1 += __shfl_down(ss1, 16);
  if (lane < 16) {
    atomicAdd(&csum[row16], s0); atomicAdd(&css[row16], ss0);
    atomicAdd(&csum[16 + row16], s1); atomicAdd(&css[16 + row16], ss1);
  }
  __syncthreads();
  if (tid < 32) {
    part2[tid * 2048 + n] = csum[tid];
    part2[(32 + tid) * 2048 + n] = css[tid];
  }
}

// ---------------------------------------------------------------- K3: conv2 recompute (144 px, window-permuted) + bn2+relu+pool2 -> p2 + conv3 partials
__global__ __launch_bounds__(256) void conv2_apply_conv3_stats(
    const us* __restrict__ p1g, const us* __restrict__ wt2L,
    const float* __restrict__ cb2, const float* __restrict__ stats2,
    const us* __restrict__ wt3L, const float* __restrict__ cb3,
    float* __restrict__ part3, us* __restrict__ p2g) {
  __shared__ __align__(16) us p1b[9000];      // [225][40]
  __shared__ __align__(16) us wt2[11520];
  __shared__ __align__(16) us p2b[1440];      // [36][40] pooled bf16
  __shared__ float scS[32], shS[32], csum[32], css[32];
  const int n = blockIdx.x, tid = threadIdx.x;
  const int wave = tid >> 6, lane = tid & 63, row16 = lane & 15, kg = lane >> 4;
  for (int i = tid; i < 900; i += 256) {
    const uint4 v = *(const uint4*)(p1g + (size_t)n * 7200 + i * 8);
    *(uint4*)&p1b[(i >> 2) * 40 + (i & 3) * 8] = v;
  }
  for (int i = tid; i < 1440; i += 256) ((uint4*)wt2)[i] = ((const uint4*)wt2L)[i];
  if (tid < 32) {
    scS[tid] = stats2[tid]; shS[tid] = stats2[32 + tid];
    csum[tid] = 0.f; css[tid] = 0.f;
  }
  __syncthreads();
  // window-permuted A rows: row q (0..143) = window q>>2, elem q&3
  int inb[3], mtv[3];
#pragma unroll
  for (int m = 0; m < 3; ++m) {
    const int mt = wave + 4 * m;
    mtv[m] = mt;
    const int pixA = (mt < 9) ? (mt * 16 + row16) : row16;
    const int w = pixA >> 2, e = pixA & 3;
    const int oi = 2 * (w / 6) + (e >> 1), oj = 2 * (w % 6) + (e & 1);
    inb[m] = oi * 15 + oj;
  }
  const float b20 = cb2[row16], b21 = cb2[16 + row16];
  f32x4 acc[3][2];
#pragma unroll
  for (int m = 0; m < 3; ++m) {
    acc[m][0] = {b20, b20, b20, b20};
    acc[m][1] = {b21, b21, b21, b21};
  }
#pragma unroll
  for (int tap = 0; tap < 9; ++tap) {
    const int ki = tap / 3, kj = tap % 3;
    const s16x8 bf0 = *(const s16x8*)&wt2[(tap * 32 + row16) * 40 + kg * 8];
    const s16x8 bf1 = *(const s16x8*)&wt2[(tap * 32 + 16 + row16) * 40 + kg * 8];
#pragma unroll
    for (int m = 0; m < 3; ++m) {
      if (mtv[m] < 9) {                       // wave-uniform
        const s16x8 a = *(const s16x8*)&p1b[(inb[m] + ki * 15 + kj) * 40 + kg * 8];
        acc[m][0] = __builtin_amdgcn_mfma_f32_16x16x32_bf16(a, bf0, acc[m][0], 0, 0, 0);
        acc[m][1] = __builtin_amdgcn_mfma_f32_16x16x32_bf16(a, bf1, acc[m][1], 0, 0, 0);
      }
    }
  }
  // in-register pool: lane's 4 C-rows (kg*4+r) = one full window (mt*4+kg)
  const float sc0 = scS[row16], sh0 = shS[row16];
  const float sc1 = scS[16 + row16], sh1 = shS[16 + row16];
#pragma unroll
  for (int m = 0; m < 3; ++m) {
    if (mtv[m] < 9) {
      float p0 = 0.f, p1v = 0.f;
#pragma unroll
      for (int r = 0; r < 4; ++r) {
        p0 += fmaxf(acc[m][0][r] * sc0 + sh0, 0.f);
        p1v += fmaxf(acc[m][1][r] * sc1 + sh1, 0.f);
      }
      const int wl = mtv[m] * 4 + kg;         // window 0..35
      p2b[wl * 40 + row16] = f2bf(p0 * 0.25f);
      p2b[wl * 40 + 16 + row16] = f2bf(p1v * 0.25f);
    }
  }
  __syncthreads();
  if (tid < 144) {                            // coalesced copy LDS -> p2g
    const int row = tid >> 2, col = (tid & 3) * 8;
    const uint4 v = *(const uint4*)&p2b[row * 40 + col];
    *(uint4*)(p2g + (size_t)n * 1152 + tid * 8) = v;
  }
  __syncthreads();
  if (wave < 2) {                              // conv3 stats (16 out px, 1 m-tile)
    const int ocb = wave * 16;
    const int inb3 = (row16 >> 2) * 6 + (row16 & 3);
    const float b3 = cb3[ocb + row16];
    f32x4 a3 = {b3, b3, b3, b3};
#pragma unroll
    for (int tap = 0; tap < 9; ++tap) {
      const int ki = tap / 3, kj = tap % 3;
      const s16x8 bf = *(const s16x8*)&wt3L[(tap * 32 + ocb + row16) * 40 + kg * 8];
      const s16x8 a = *(const s16x8*)&p2b[(inb3 + ki * 6 + kj) * 40 + kg * 8];
      a3 = __builtin_amdgcn_mfma_f32_16x16x32_bf16(a, bf, a3, 0, 0, 0);
    }
    float s = a3[0] + a3[1] + a3[2] + a3[3];
    float ss = a3[0]*a3[0] + a3[1]*a3[1] + a3[2]*a3[2] + a3[3]*a3[3];
    s += __shfl_down(s, 32); s += __shfl_down(s, 16);
    ss += __shfl_down(ss, 32); ss += __shfl_down(ss, 16);
    if (lane < 16) { atomicAdd(&csum[ocb + row16], s); atomicAdd(&css[ocb + row16], ss); }
  }
  __syncthreads();
  if (tid < 32) {
    part3[tid * 2048 + n] = csum[tid];
    part3[(32 + tid) * 2048 + n] = css[tid];
  }
}

// ---------------------------------------------------------------- K4: conv3 recompute (window-permuted) + bn3+relu+pool3 -> h0 (8 samples/block)
__global__ __launch_bounds__(256) void conv3_apply(
    const us* __restrict__ p2g, const us* __restrict__ wt3L,
    const float* __restrict__ cb3, const float* __restrict__ stats3,
    float* __restrict__ h0g) {
  __shared__ __align__(16) us p2L[11520];      // [8][36][40]
  __shared__ __align__(16) us wt3[11520];
  __shared__ float scS[32], shS[32];
  __shared__ float h0a[1024];
  const int n0 = blockIdx.x * 8, tid = threadIdx.x;
  const int wave = tid >> 6, lane = tid & 63, row16 = lane & 15, kg = lane >> 4;
  for (int i = tid; i < 1152; i += 256) {
    const int s = i / 144, ci = i - s * 144;
    const uint4 v = *(const uint4*)(p2g + (size_t)n0 * 1152 + i * 8);
    *(uint4*)&p2L[(s * 36 + (ci >> 2)) * 40 + (ci & 3) * 8] = v;
  }
  for (int i = tid; i < 1440; i += 256) ((uint4*)wt3)[i] = ((const uint4*)wt3L)[i];
  if (tid < 32) { scS[tid] = stats3[tid]; shS[tid] = stats3[32 + tid]; }
  __syncthreads();
  // permuted A row: q = w*4+e, w=pool-window (raster 2x2), e=elem
  const int wA = row16 >> 2, eA = row16 & 3;
  const int inb3 = (2 * (wA >> 1) + (eA >> 1)) * 6 + 2 * (wA & 1) + (eA & 1);
  const float b30 = cb3[row16], b31 = cb3[16 + row16];
  f32x4 accA[2][2];
#pragma unroll
  for (int si = 0; si < 2; ++si) {
    accA[si][0] = {b30, b30, b30, b30};
    accA[si][1] = {b31, b31, b31, b31};
  }
#pragma unroll
  for (int tap = 0; tap < 9; ++tap) {
    const int ki = tap / 3, kj = tap % 3;
    const s16x8 bf0 = *(const s16x8*)&wt3[(tap * 32 + row16) * 40 + kg * 8];
    const s16x8 bf1 = *(const s16x8*)&wt3[(tap * 32 + 16 + row16) * 40 + kg * 8];
#pragma unroll
    for (int si = 0; si < 2; ++si) {
      const int s = wave + 4 * si;
      const s16x8 a = *(const s16x8*)&p2L[(s * 36 + inb3 + ki * 6 + kj) * 40 + kg * 8];
      accA[si][0] = __builtin_amdgcn_mfma_f32_16x16x32_bf16(a, bf0, accA[si][0], 0, 0, 0);
      accA[si][1] = __builtin_amdgcn_mfma_f32_16x16x32_bf16(a, bf1, accA[si][1], 0, 0, 0);
    }
  }
  // in-register pool: lane's 4 C-rows = window kg; h0[s][c*4 + kg]
  const float sc0 = scS[row16], sh0 = shS[row16];
  const float sc1 = scS[16 + row16], sh1 = shS[16 + row16];
#pragma unroll
  for (int si = 0; si < 2; ++si) {
    const int s = wave + 4 * si;
    float p0 = 0.f, p1v = 0.f;
#pragma unroll
    for (int r = 0; r < 4; ++r) {
      p0 += fmaxf(accA[si][0][r] * sc0 + sh0, 0.f);
      p1v += fmaxf(accA[si][1][r] * sc1 + sh1, 0.f);
    }
    h0a[s * 128 + row16 * 4 + kg] = p0 * 0.25f;
    h0a[s * 128 + (16 + row16) * 4 + kg] = p1v * 0.25f;
  }
  __syncthreads();
  ((float4*)(h0g + (size_t)n0 * 128))[tid] = ((const float4*)h0a)[tid];
}

// ---------------------------------------------------------------- K5: MFMA routed MLP
#define STR 136
__global__ __launch_bounds__(256) void mlp2_kernel(
    const float* __restrict__ h0, const float* __restrict__ traj,
    const float* __restrict__ eW, const float* __restrict__ eb,
    const float* __restrict__ oW, const float* __restrict__ ob,
    float* __restrict__ out) {
  __shared__ __align__(16) us wexp[3 * 128 * STR];
  __shared__ __align__(16) us owl[112 * STR];
  __shared__ __align__(16) us htile[4][16 * STR];
  __shared__ float ebl[384];
  __shared__ float obl[112];
  const int tid = threadIdx.x, wave = tid >> 6, lane = tid & 63;
  const int row16 = lane & 15, kg = lane >> 4;
  const int rbase = blockIdx.x * 64 + wave * 16;
  for (int i = tid; i < 12288; i += 256) {
    const int e = i >> 12, rem = i & 4095, o = rem >> 5, d4 = (rem & 31) * 4;
    const float4 v = *(const float4*)(eW + ((e * 128 + o) * 128 + d4));
    const unsigned lo = f2bf(v.x) | ((unsigned)f2bf(v.y) << 16);
    const unsigned hi = f2bf(v.z) | ((unsigned)f2bf(v.w) << 16);
    *(uint2*)&wexp[(e * 128 + o) * STR + d4] = make_uint2(lo, hi);
  }
  for (int i = tid; i < 112 * 32; i += 256) {
    const int cls = i >> 5, d4 = (i & 31) * 4;
    float4 v = make_float4(0.f, 0.f, 0.f, 0.f);
    if (cls < 100) v = *(const float4*)(oW + cls * 128 + d4);
    const unsigned lo = f2bf(v.x) | ((unsigned)f2bf(v.y) << 16);
    const unsigned hi = f2bf(v.z) | ((unsigned)f2bf(v.w) << 16);
    *(uint2*)&owl[cls * STR + d4] = make_uint2(lo, hi);
  }
  for (int i = tid; i < 384; i += 256) ebl[i] = eb[i];
  if (tid < 112) obl[tid] = (tid < 100) ? ob[tid] : 0.f;
  us* ht = &htile[wave][0];
  for (int i = lane; i < 256; i += 64) {
    const int row = i >> 4, d8 = (i & 15) * 8;
    const int rowg = rbase + row;
    const float4 v0 = *(const float4*)(h0 + (size_t)(rowg >> 1) * 128 + d8);
    const float4 v1 = *(const float4*)(h0 + (size_t)(rowg >> 1) * 128 + d8 + 4);
    uint4 p;
    p.x = f2bf(v0.x) | ((unsigned)f2bf(v0.y) << 16);
    p.y = f2bf(v0.z) | ((unsigned)f2bf(v0.w) << 16);
    p.z = f2bf(v1.x) | ((unsigned)f2bf(v1.y) << 16);
    p.w = f2bf(v1.z) | ((unsigned)f2bf(v1.w) << 16);
    *(uint4*)&ht[row * STR + d8] = p;
  }
  __syncthreads();
  float accv[8][4];
#pragma unroll
  for (int ct = 0; ct < 8; ++ct)
#pragma unroll
    for (int r = 0; r < 4; ++r) {
      const int rowg = rbase + kg * 4 + r;
      accv[ct][r] = h0[(size_t)(rowg >> 1) * 128 + ct * 16 + row16];
    }
  for (int d = 0; d < 3; ++d) {
    int sel[4];
#pragma unroll
    for (int r = 0; r < 4; ++r) {
      const int rowg = rbase + kg * 4 + r;
      const float4 t4 = *(const float4*)(traj + d * 16384 + rowg * 4);
      int s = 0; float mx = t4.x;
      if (t4.y > mx) { mx = t4.y; s = 1; }
      if (t4.z > mx) { mx = t4.z; s = 2; }
      if (t4.w > mx) { mx = t4.w; s = 3; }
      sel[r] = s;
    }
    s16x8 a[4];
#pragma unroll
    for (int kc = 0; kc < 4; ++kc)
      a[kc] = *(const s16x8*)&ht[row16 * STR + kc * 32 + kg * 8];
    float newacc[8][4];
#pragma unroll
    for (int ct = 0; ct < 8; ++ct)
#pragma unroll
      for (int r = 0; r < 4; ++r)
        newacc[ct][r] = (sel[r] == 3) ? accv[ct][r] : 0.f;
#pragma unroll
    for (int e = 0; e < 3; ++e) {
#pragma unroll
      for (int ct = 0; ct < 8; ++ct) {
        f32x4 t = {0.f, 0.f, 0.f, 0.f};
#pragma unroll
        for (int kc = 0; kc < 4; ++kc) {
          const s16x8 b = *(const s16x8*)&wexp[(e * 128 + ct * 16 + row16) * STR + kc * 32 + kg * 8];
          t = __builtin_amdgcn_mfma_f32_16x16x32_bf16(a[kc], b, t, 0, 0, 0);
        }
        const float bias = ebl[e * 128 + ct * 16 + row16];
#pragma unroll
        for (int r = 0; r < 4; ++r)
          if (sel[r] == e) newacc[ct][r] = t[r] + bias;
      }
    }
#pragma unroll
    for (int ct = 0; ct < 8; ++ct)
#pragma unroll
      for (int r = 0; r < 4; ++r) {
        float v = newacc[ct][r];
        if (d < 2) v = fmaxf(v, 0.f);
        accv[ct][r] = v;
        ht[(kg * 4 + r) * STR + ct * 16 + row16] = f2bf(v);
      }
  }
  s16x8 a[4];
#pragma unroll
  for (int kc = 0; kc < 4; ++kc)
    a[kc] = *(const s16x8*)&ht[row16 * STR + kc * 32 + kg * 8];
  float preds[7][4];
#pragma unroll
  for (int ct = 0; ct < 7; ++ct) {
    f32x4 t = {0.f, 0.f, 0.f, 0.f};
#pragma unroll
    for (int kc = 0; kc < 4; ++kc) {
      const s16x8 b = *(const s16x8*)&owl[(ct * 16 + row16) * STR + kc * 32 + kg * 8];
      t = __builtin_amdgcn_mfma_f32_16x16x32_bf16(a[kc], b, t, 0, 0, 0);
    }
    const float bias = obl[ct * 16 + row16];
#pragma unroll
    for (int r = 0; r < 4; ++r) preds[ct][r] = t[r] + bias;
  }
  const bool v6 = (96 + row16) < 100;
#pragma unroll
  for (int r = 0; r < 4; ++r) {
    float mx = -INFINITY;
#pragma unroll
    for (int ct = 0; ct < 7; ++ct)
      if (ct < 6 || v6) mx = fmaxf(mx, preds[ct][r]);
    mx = fmaxf(mx, __shfl_xor(mx, 1)); mx = fmaxf(mx, __shfl_xor(mx, 2));
    mx = fmaxf(mx, __shfl_xor(mx, 4)); mx = fmaxf(mx, __shfl_xor(mx, 8));
    float s = 0.f;
#pragma unroll
    for (int ct = 0; ct < 7; ++ct)
      if (ct < 6 || v6) s += expf(preds[ct][r] - mx);
    s += __shfl_xor(s, 1); s += __shfl_xor(s, 2);
    s += __shfl_xor(s, 4); s += __shfl_xor(s, 8);
    const float lg = mx + logf(s);
    const int rowg = rbase + kg * 4 + r;
#pragma unroll
    for (int ct = 0; ct < 7; ++ct)
      if (ct < 6 || v6) out[(size_t)rowg * 100 + ct * 16 + row16] = preds[ct][r] - lg;
  }
}

// ---------------------------------------------------------------- launch
extern "C" void kernel_launch(void* const* d_in, const int* in_sizes, int n_in,
                              void* d_out, int out_size, void* d_ws, size_t ws_size,
                              hipStream_t stream) {
  const float* x     = (const float*)d_in[0];
  const float* traj  = (const float*)d_in[1];
  const float* score = (const float*)d_in[2];
  const float* cw1 = (const float*)d_in[3];
  const float* cb1 = (const float*)d_in[4];
  const float* g1  = (const float*)d_in[5];
  const float* bb1 = (const float*)d_in[6];
  const float* cw2 = (const float*)d_in[7];
  const float* cb2 = (const float*)d_in[8];
  const float* g2  = (const float*)d_in[9];
  const float* bb2 = (const float*)d_in[10];
  const float* cw3 = (const float*)d_in[11];
  const float* cb3 = (const float*)d_in[12];
  const float* g3  = (const float*)d_in[13];
  const float* bb3 = (const float*)d_in[14];
  const float* eW  = (const float*)d_in[15];
  const float* eb  = (const float*)d_in[16];
  const float* oW  = (const float*)d_in[17];
  const float* ob  = (const float*)d_in[18];
  float* out = (float*)d_out;

  char* ws = (char*)d_ws;
  float* stats1 = (float*)ws;                    // 64 f32 {sc,sh}
  float* stats2 = (float*)(ws + 256);
  float* stats3 = (float*)(ws + 512);
  us* wt1L = (us*)(ws + 1024);
  us* wt2L = (us*)(ws + 4096);
  us* wt3L = (us*)(ws + 4096 + 23040);
  us* p1g  = (us*)(ws + 65536);                  // bf16 [2048][225][32]
  us* p2g  = (us*)(ws + 65536 + 29491200);       // bf16 [2048][36][32]
  float* h0g = (float*)(ws + 65536 + 29491200 + 4718592);  // f32 [2048][128]
  char* pbase = ws + 65536 + 29491200 + 4718592 + 1048576;
  float* part1 = (float*)pbase;                  // [64][2048]
  float* part2 = (float*)(pbase + 524288);
  float* part3 = (float*)(pbase + 1048576);

  prep_weights<<<12, 256, 0, stream>>>(cw1, cw2, cw3, wt1L, wt2L, wt3L);
  conv1_stats<<<2048, 256, 0, stream>>>(x, wt1L, cb1, part1);
  finalize_stats<<<32, 256, 0, stream>>>(part1, g1, bb1, 2048.f * 900.f, stats1);
  conv1_apply_conv2_stats<<<2048, 256, 0, stream>>>(x, wt1L, cb1, stats1,
                                                    wt2L, cb2, part2, p1g);
  finalize_stats<<<32, 256, 0, stream>>>(part2, g2, bb2, 2048.f * 169.f, stats2);
  conv2_apply_conv3_stats<<<2048, 256, 0, stream>>>(p1g, wt2L, cb2, stats2,
                                                    wt3L, cb3, part3, p2g);
  finalize_stats<<<32, 256, 0, stream>>>(part3, g3, bb3, 2048.f * 16.f, stats3);
  conv3_apply<<<256, 256, 0, stream>>>(p2g, wt3L, cb3, stats3, h0g);
  mlp2_kernel<<<64, 256, 0, stream>>>(h0g, traj, eW, eb, oW, ob, out);
  hipMemcpyAsync(out + 409600, score, 4096 * sizeof(float),
                 hipMemcpyDeviceToDevice, stream);
}

// Round 9
// 129.946 us; speedup vs baseline: 4.1230x; 1.0999x over previous
//
#include <hip/hip_runtime.h>
#include <math.h>

typedef unsigned short us;
typedef short s16x8 __attribute__((ext_vector_type(8)));
typedef float f32x4 __attribute__((ext_vector_type(4)));

#define EPSV 1e-5f

static __device__ inline us f2bf(float f) {            // RNE f32->bf16 (finite inputs)
  union { float f; unsigned u; } v; v.f = f;
  unsigned r = v.u + 0x7fffu + ((v.u >> 16) & 1u);
  return (us)(r >> 16);
}

// conv1 A-fragment k->offset table
#define SET8(o,a,b,c,d,e,f,g,h) {o[0]=a;o[1]=b;o[2]=c;o[3]=d;o[4]=e;o[5]=f;o[6]=g;o[7]=h;}
static __device__ inline void c1_offsets(int kg, int* offs) {
  switch (kg) {
    case 0: SET8(offs, 0, 1, 2, 32, 33, 34, 64, 65); break;
    case 1: SET8(offs, 66, 1024, 1025, 1026, 1056, 1057, 1058, 1088); break;
    case 2: SET8(offs, 1089, 1090, 2048, 2049, 2050, 2080, 2081, 2082); break;
    default: SET8(offs, 2112, 2113, 2114, 3072, 3072, 3072, 3072, 3072); break;
  }
}

union AU { s16x8 v; us e[8]; };

// ---------------------------------------------------------------- K0: preconvert conv weights
__global__ __launch_bounds__(256) void prep_weights(
    const float* __restrict__ w1, const float* __restrict__ w2,
    const float* __restrict__ w3, us* __restrict__ wt1L,
    us* __restrict__ wt2L, us* __restrict__ wt3L) {
  const int tid = blockIdx.x * 256 + threadIdx.x;
  if (tid < 1280) {
    const int oc = tid / 40, k = tid % 40;
    wt1L[tid] = (k < 27) ? f2bf(w1[oc * 27 + k]) : (us)0;
  }
  for (int i = tid; i < 11520; i += gridDim.x * 256) {
    const int row = i / 40, col = i % 40;
    const int tap = row >> 5, oc = row & 31;
    wt2L[i] = (col < 32) ? f2bf(w2[oc * 288 + col * 9 + tap]) : (us)0;
    wt3L[i] = (col < 32) ? f2bf(w3[oc * 288 + col * 9 + tap]) : (us)0;
  }
}

// ---------------------------------------------------------------- finalize: partials[ch][2048] -> {scale, shift}
__global__ __launch_bounds__(256) void finalize_stats(
    const float* __restrict__ part, const float* __restrict__ g,
    const float* __restrict__ bb, float cnt, float* __restrict__ stats) {
  __shared__ float redS[256], redQ[256];
  const int ch = blockIdx.x, tid = threadIdx.x;
  const float* ps = part + (size_t)ch * 2048;
  const float* pq = part + (size_t)(32 + ch) * 2048;
  float s = 0.f, q = 0.f;
  for (int i = tid; i < 2048; i += 256) { s += ps[i]; q += pq[i]; }
  redS[tid] = s; redQ[tid] = q;
  __syncthreads();
  for (int off = 128; off; off >>= 1) {
    if (tid < off) { redS[tid] += redS[tid + off]; redQ[tid] += redQ[tid + off]; }
    __syncthreads();
  }
  if (tid == 0) {
    const float mean = redS[0] / cnt;
    const float var = redQ[0] / cnt - mean * mean;
    const float sc = g[ch] * rsqrtf(var + EPSV);
    stats[ch] = sc;
    stats[32 + ch] = bb[ch] - mean * sc;
  }
}

// ---------------------------------------------------------------- K1: conv1 stats only
__global__ __launch_bounds__(256) void conv1_stats(
    const float* __restrict__ x, const us* __restrict__ wt1L,
    const float* __restrict__ cb, float* __restrict__ part1) {
  __shared__ __align__(16) us xsb[4096];
  __shared__ float csum[32], css[32];
  const int n = blockIdx.x, tid = threadIdx.x;
  const int wave = tid >> 6, lane = tid & 63, row16 = lane & 15, kg = lane >> 4;
  const float4* xp = (const float4*)(x + (size_t)n * 3072);
  for (int i = tid; i < 768; i += 256) {
    const float4 v = xp[i];
    const unsigned lo = f2bf(v.x) | ((unsigned)f2bf(v.y) << 16);
    const unsigned hi = f2bf(v.z) | ((unsigned)f2bf(v.w) << 16);
    *(uint2*)&xsb[i * 4] = make_uint2(lo, hi);
  }
  if (tid < 256) *(uint2*)&xsb[3072 + tid * 4] = make_uint2(0, 0);
  if (tid < 32) { csum[tid] = 0.f; css[tid] = 0.f; }
  __syncthreads();
  int offs[8]; c1_offsets(kg, offs);
  const s16x8 bf0 = *(const s16x8*)&wt1L[row16 * 40 + kg * 8];
  const s16x8 bf1 = *(const s16x8*)&wt1L[(16 + row16) * 40 + kg * 8];
  const float bias0 = cb[row16], bias1 = cb[16 + row16];
  float s0 = 0.f, ss0 = 0.f, s1 = 0.f, ss1 = 0.f;
  for (int t = wave; t < 60; t += 4) {        // tile = 2 rows x 8 cols
    const int ip = t >> 2, cg = t & 3;
    const int ai = 2 * ip + (row16 >> 3), aj = cg * 8 + (row16 & 7);
    const int base = (aj < 30) ? (ai * 32 + aj) : 0;
    AU a;
#pragma unroll
    for (int q = 0; q < 8; ++q) a.e[q] = xsb[base + offs[q]];
    f32x4 acc0 = {bias0, bias0, bias0, bias0};
    f32x4 acc1 = {bias1, bias1, bias1, bias1};
    acc0 = __builtin_amdgcn_mfma_f32_16x16x32_bf16(a.v, bf0, acc0, 0, 0, 0);
    acc1 = __builtin_amdgcn_mfma_f32_16x16x32_bf16(a.v, bf1, acc1, 0, 0, 0);
#pragma unroll
    for (int r = 0; r < 4; ++r) {
      const int jc = cg * 8 + (kg & 1) * 4 + r;
      if (jc < 30) {
        s0 += acc0[r]; ss0 += acc0[r] * acc0[r];
        s1 += acc1[r]; ss1 += acc1[r] * acc1[r];
      }
    }
  }
  s0 += __shfl_down(s0, 32); s0 += __shfl_down(s0, 16);
  ss0 += __shfl_down(ss0, 32); ss0 += __shfl_down(ss0, 16);
  s1 += __shfl_down(s1, 32); s1 += __shfl_down(s1, 16);
  ss1 += __shfl_down(ss1, 32); ss1 += __shfl_down(ss1, 16);
  if (lane < 16) {
    atomicAdd(&csum[row16], s0); atomicAdd(&css[row16], ss0);
    atomicAdd(&csum[16 + row16], s1); atomicAdd(&css[16 + row16], ss1);
  }
  __syncthreads();
  if (tid < 32) {
    part1[tid * 2048 + n] = csum[tid];
    part1[(32 + tid) * 2048 + n] = css[tid];
  }
}

// ---------------------------------------------------------------- K2: conv1 (window-permuted) + bn1+relu+pool1 -> p1 + conv2 partials
__global__ __launch_bounds__(256) void conv1_apply_conv2_stats(
    const float* __restrict__ x, const us* __restrict__ wt1L,
    const float* __restrict__ cb1, const float* __restrict__ stats1,
    const us* __restrict__ wt2L, const float* __restrict__ cb2,
    float* __restrict__ part2, us* __restrict__ p1g) {
  __shared__ __align__(16) us xsb[4096];
  __shared__ __align__(16) us p1b[9000];      // [225][40]
  __shared__ float scS[32], shS[32], csum[32], css[32];
  const int n = blockIdx.x, tid = threadIdx.x;
  const int wave = tid >> 6, lane = tid & 63, row16 = lane & 15, kg = lane >> 4;
  const float4* xp = (const float4*)(x + (size_t)n * 3072);
  for (int i = tid; i < 768; i += 256) {
    const float4 v = xp[i];
    const unsigned lo = f2bf(v.x) | ((unsigned)f2bf(v.y) << 16);
    const unsigned hi = f2bf(v.z) | ((unsigned)f2bf(v.w) << 16);
    *(uint2*)&xsb[i * 4] = make_uint2(lo, hi);
  }
  if (tid < 256) *(uint2*)&xsb[3072 + tid * 4] = make_uint2(0, 0);
  if (tid < 32) {
    scS[tid] = stats1[tid]; shS[tid] = stats1[32 + tid];
    csum[tid] = 0.f; css[tid] = 0.f;
  }
  __syncthreads();
  int offs[8]; c1_offsets(kg, offs);
  {
    const s16x8 bf0 = *(const s16x8*)&wt1L[row16 * 40 + kg * 8];
    const s16x8 bf1 = *(const s16x8*)&wt1L[(16 + row16) * 40 + kg * 8];
    const float bias0 = cb1[row16], bias1 = cb1[16 + row16];
    const float sc0 = scS[row16], sh0 = shS[row16];
    const float sc1 = scS[16 + row16], sh1 = shS[16 + row16];
    // window-permuted A rows: row q (0..899) = window q>>2 (15x15 raster), elem q&3
    for (int mt = wave; mt < 57; mt += 4) {
      const int pixA = mt * 16 + row16;
      int base = 0;
      if (pixA < 900) {
        const int w = pixA >> 2, e = pixA & 3;
        base = (2 * (w / 15) + (e >> 1)) * 32 + 2 * (w % 15) + (e & 1);
      }
      AU a;
#pragma unroll
      for (int q = 0; q < 8; ++q) a.e[q] = xsb[base + offs[q]];
      f32x4 acc0 = {bias0, bias0, bias0, bias0};
      f32x4 acc1 = {bias1, bias1, bias1, bias1};
      acc0 = __builtin_amdgcn_mfma_f32_16x16x32_bf16(a.v, bf0, acc0, 0, 0, 0);
      acc1 = __builtin_amdgcn_mfma_f32_16x16x32_bf16(a.v, bf1, acc1, 0, 0, 0);
      const int w = mt * 4 + kg;              // pooled pixel 0..224
      if (w < 225) {
        float p0 = 0.f, p1v = 0.f;
#pragma unroll
        for (int r = 0; r < 4; ++r) {
          p0 += fmaxf(acc0[r] * sc0 + sh0, 0.f);
          p1v += fmaxf(acc1[r] * sc1 + sh1, 0.f);
        }
        p1b[w * 40 + row16] = f2bf(p0 * 0.25f);
        p1b[w * 40 + 16 + row16] = f2bf(p1v * 0.25f);
      }
    }
  }
  __syncthreads();
  // write p1 (bf16) coalesced
  for (int i = tid; i < 900; i += 256) {
    const uint4 v = *(const uint4*)&p1b[(i >> 2) * 40 + (i & 3) * 8];
    *(uint4*)(p1g + (size_t)n * 7200 + i * 8) = v;
  }
  // conv2 stats from LDS p1 (full 169 raster); B-fragments direct from global
  int inb[3];
#pragma unroll
  for (int m = 0; m < 3; ++m) {
    int pixA = (wave + 4 * m) * 16 + row16;
    if (pixA >= 169) pixA = 0;
    const int oi = pixA / 13, oj = pixA - 13 * oi;
    inb[m] = oi * 15 + oj;
  }
  const float b20 = cb2[row16], b21 = cb2[16 + row16];
  f32x4 acc[3][2];
#pragma unroll
  for (int m = 0; m < 3; ++m) {
    acc[m][0] = {b20, b20, b20, b20};
    acc[m][1] = {b21, b21, b21, b21};
  }
#pragma unroll
  for (int tap = 0; tap < 9; ++tap) {
    const int ki = tap / 3, kj = tap % 3;
    const s16x8 bf0 = *(const s16x8*)&wt2L[(tap * 32 + row16) * 40 + kg * 8];
    const s16x8 bf1 = *(const s16x8*)&wt2L[(tap * 32 + 16 + row16) * 40 + kg * 8];
#pragma unroll
    for (int m = 0; m < 3; ++m) {
      const s16x8 a = *(const s16x8*)&p1b[(inb[m] + ki * 15 + kj) * 40 + kg * 8];
      acc[m][0] = __builtin_amdgcn_mfma_f32_16x16x32_bf16(a, bf0, acc[m][0], 0, 0, 0);
      acc[m][1] = __builtin_amdgcn_mfma_f32_16x16x32_bf16(a, bf1, acc[m][1], 0, 0, 0);
    }
  }
  float s0 = 0.f, ss0 = 0.f, s1 = 0.f, ss1 = 0.f;
#pragma unroll
  for (int m = 0; m < 3; ++m)
#pragma unroll
    for (int r = 0; r < 4; ++r) {
      const int pix = (wave + 4 * m) * 16 + kg * 4 + r;
      if (pix < 169) {
        const float u0 = acc[m][0][r], u1 = acc[m][1][r];
        s0 += u0; ss0 += u0 * u0; s1 += u1; ss1 += u1 * u1;
      }
    }
  s0 += __shfl_down(s0, 32); s0 += __shfl_down(s0, 16);
  ss0 += __shfl_down(ss0, 32); ss0 += __shfl_down(ss0, 16);
  s1 += __shfl_down(s1, 32); s1 += __shfl_down(s1, 16);
  ss1 += __shfl_down(ss1, 32); ss1 += __shfl_down(ss1, 16);
  if (lane < 16) {
    atomicAdd(&csum[row16], s0); atomicAdd(&css[row16], ss0);
    atomicAdd(&csum[16 + row16], s1); atomicAdd(&css[16 + row16], ss1);
  }
  __syncthreads();
  if (tid < 32) {
    part2[tid * 2048 + n] = csum[tid];
    part2[(32 + tid) * 2048 + n] = css[tid];
  }
}

// ---------------------------------------------------------------- K3: conv2 (window-permuted) + bn2+relu+pool2 -> p2 + conv3 partials
__global__ __launch_bounds__(256) void conv2_apply_conv3_stats(
    const us* __restrict__ p1g, const us* __restrict__ wt2L,
    const float* __restrict__ cb2, const float* __restrict__ stats2,
    const us* __restrict__ wt3L, const float* __restrict__ cb3,
    float* __restrict__ part3, us* __restrict__ p2g) {
  __shared__ __align__(16) us p1b[9000];      // [225][40]
  __shared__ __align__(16) us p2b[1440];      // [36][40] pooled bf16
  __shared__ float scS[32], shS[32], csum[32], css[32];
  const int n = blockIdx.x, tid = threadIdx.x;
  const int wave = tid >> 6, lane = tid & 63, row16 = lane & 15, kg = lane >> 4;
  for (int i = tid; i < 900; i += 256) {
    const uint4 v = *(const uint4*)(p1g + (size_t)n * 7200 + i * 8);
    *(uint4*)&p1b[(i >> 2) * 40 + (i & 3) * 8] = v;
  }
  if (tid < 32) {
    scS[tid] = stats2[tid]; shS[tid] = stats2[32 + tid];
    csum[tid] = 0.f; css[tid] = 0.f;
  }
  __syncthreads();
  // window-permuted A rows: row q (0..143) = window q>>2, elem q&3
  int inb[3], mtv[3];
#pragma unroll
  for (int m = 0; m < 3; ++m) {
    const int mt = wave + 4 * m;
    mtv[m] = mt;
    const int pixA = (mt < 9) ? (mt * 16 + row16) : row16;
    const int w = pixA >> 2, e = pixA & 3;
    const int oi = 2 * (w / 6) + (e >> 1), oj = 2 * (w % 6) + (e & 1);
    inb[m] = oi * 15 + oj;
  }
  const float b20 = cb2[row16], b21 = cb2[16 + row16];
  f32x4 acc[3][2];
#pragma unroll
  for (int m = 0; m < 3; ++m) {
    acc[m][0] = {b20, b20, b20, b20};
    acc[m][1] = {b21, b21, b21, b21};
  }
#pragma unroll
  for (int tap = 0; tap < 9; ++tap) {
    const int ki = tap / 3, kj = tap % 3;
    const s16x8 bf0 = *(const s16x8*)&wt2L[(tap * 32 + row16) * 40 + kg * 8];
    const s16x8 bf1 = *(const s16x8*)&wt2L[(tap * 32 + 16 + row16) * 40 + kg * 8];
#pragma unroll
    for (int m = 0; m < 3; ++m) {
      if (mtv[m] < 9) {                       // wave-uniform
        const s16x8 a = *(const s16x8*)&p1b[(inb[m] + ki * 15 + kj) * 40 + kg * 8];
        acc[m][0] = __builtin_amdgcn_mfma_f32_16x16x32_bf16(a, bf0, acc[m][0], 0, 0, 0);
        acc[m][1] = __builtin_amdgcn_mfma_f32_16x16x32_bf16(a, bf1, acc[m][1], 0, 0, 0);
      }
    }
  }
  // in-register pool: lane's 4 C-rows (kg*4+r) = one full window (mt*4+kg)
  const float sc0 = scS[row16], sh0 = shS[row16];
  const float sc1 = scS[16 + row16], sh1 = shS[16 + row16];
#pragma unroll
  for (int m = 0; m < 3; ++m) {
    if (mtv[m] < 9) {
      float p0 = 0.f, p1v = 0.f;
#pragma unroll
      for (int r = 0; r < 4; ++r) {
        p0 += fmaxf(acc[m][0][r] * sc0 + sh0, 0.f);
        p1v += fmaxf(acc[m][1][r] * sc1 + sh1, 0.f);
      }
      const int wl = mtv[m] * 4 + kg;         // window 0..35
      p2b[wl * 40 + row16] = f2bf(p0 * 0.25f);
      p2b[wl * 40 + 16 + row16] = f2bf(p1v * 0.25f);
    }
  }
  __syncthreads();
  if (tid < 144) {                            // coalesced copy LDS -> p2g
    const int row = tid >> 2, col = (tid & 3) * 8;
    const uint4 v = *(const uint4*)&p2b[row * 40 + col];
    *(uint4*)(p2g + (size_t)n * 1152 + tid * 8) = v;
  }
  __syncthreads();
  if (wave < 2) {                              // conv3 stats (16 out px, 1 m-tile)
    const int ocb = wave * 16;
    const int inb3 = (row16 >> 2) * 6 + (row16 & 3);
    const float b3 = cb3[ocb + row16];
    f32x4 a3 = {b3, b3, b3, b3};
#pragma unroll
    for (int tap = 0; tap < 9; ++tap) {
      const int ki = tap / 3, kj = tap % 3;
      const s16x8 bf = *(const s16x8*)&wt3L[(tap * 32 + ocb + row16) * 40 + kg * 8];
      const s16x8 a = *(const s16x8*)&p2b[(inb3 + ki * 6 + kj) * 40 + kg * 8];
      a3 = __builtin_amdgcn_mfma_f32_16x16x32_bf16(a, bf, a3, 0, 0, 0);
    }
    float s = a3[0] + a3[1] + a3[2] + a3[3];
    float ss = a3[0]*a3[0] + a3[1]*a3[1] + a3[2]*a3[2] + a3[3]*a3[3];
    s += __shfl_down(s, 32); s += __shfl_down(s, 16);
    ss += __shfl_down(ss, 32); ss += __shfl_down(ss, 16);
    if (lane < 16) { atomicAdd(&csum[ocb + row16], s); atomicAdd(&css[ocb + row16], ss); }
  }
  __syncthreads();
  if (tid < 32) {
    part3[tid * 2048 + n] = csum[tid];
    part3[(32 + tid) * 2048 + n] = css[tid];
  }
}

// ---------------------------------------------------------------- K4: conv3 (window-permuted) + bn3+relu+pool3 -> h0 (8 samples/block)
__global__ __launch_bounds__(256) void conv3_apply(
    const us* __restrict__ p2g, const us* __restrict__ wt3L,
    const float* __restrict__ cb3, const float* __restrict__ stats3,
    float* __restrict__ h0g) {
  __shared__ __align__(16) us p2L[11520];      // [8][36][40]
  __shared__ float scS[32], shS[32];
  __shared__ float h0a[1024];
  const int n0 = blockIdx.x * 8, tid = threadIdx.x;
  const int wave = tid >> 6, lane = tid & 63, row16 = lane & 15, kg = lane >> 4;
  for (int i = tid; i < 1152; i += 256) {
    const int s = i / 144, ci = i - s * 144;
    const uint4 v = *(const uint4*)(p2g + (size_t)n0 * 1152 + i * 8);
    *(uint4*)&p2L[(s * 36 + (ci >> 2)) * 40 + (ci & 3) * 8] = v;
  }
  if (tid < 32) { scS[tid] = stats3[tid]; shS[tid] = stats3[32 + tid]; }
  __syncthreads();
  // permuted A row: q = w*4+e, w=pool-window (raster 2x2), e=elem
  const int wA = row16 >> 2, eA = row16 & 3;
  const int inb3 = (2 * (wA >> 1) + (eA >> 1)) * 6 + 2 * (wA & 1) + (eA & 1);
  const float b30 = cb3[row16], b31 = cb3[16 + row16];
  f32x4 accA[2][2];
#pragma unroll
  for (int si = 0; si < 2; ++si) {
    accA[si][0] = {b30, b30, b30, b30};
    accA[si][1] = {b31, b31, b31, b31};
  }
#pragma unroll
  for (int tap = 0; tap < 9; ++tap) {
    const int ki = tap / 3, kj = tap % 3;
    const s16x8 bf0 = *(const s16x8*)&wt3L[(tap * 32 + row16) * 40 + kg * 8];
    const s16x8 bf1 = *(const s16x8*)&wt3L[(tap * 32 + 16 + row16) * 40 + kg * 8];
#pragma unroll
    for (int si = 0; si < 2; ++si) {
      const int s = wave + 4 * si;
      const s16x8 a = *(const s16x8*)&p2L[(s * 36 + inb3 + ki * 6 + kj) * 40 + kg * 8];
      accA[si][0] = __builtin_amdgcn_mfma_f32_16x16x32_bf16(a, bf0, accA[si][0], 0, 0, 0);
      accA[si][1] = __builtin_amdgcn_mfma_f32_16x16x32_bf16(a, bf1, accA[si][1], 0, 0, 0);
    }
  }
  // in-register pool: lane's 4 C-rows = window kg; h0[s][c*4 + kg]
  const float sc0 = scS[row16], sh0 = shS[row16];
  const float sc1 = scS[16 + row16], sh1 = shS[16 + row16];
#pragma unroll
  for (int si = 0; si < 2; ++si) {
    const int s = wave + 4 * si;
    float p0 = 0.f, p1v = 0.f;
#pragma unroll
    for (int r = 0; r < 4; ++r) {
      p0 += fmaxf(accA[si][0][r] * sc0 + sh0, 0.f);
      p1v += fmaxf(accA[si][1][r] * sc1 + sh1, 0.f);
    }
    h0a[s * 128 + row16 * 4 + kg] = p0 * 0.25f;
    h0a[s * 128 + (16 + row16) * 4 + kg] = p1v * 0.25f;
  }
  __syncthreads();
  ((float4*)(h0g + (size_t)n0 * 128))[tid] = ((const float4*)h0a)[tid];
}

// ---------------------------------------------------------------- K5: MFMA routed MLP
#define STR 136
__global__ __launch_bounds__(256) void mlp2_kernel(
    const float* __restrict__ h0, const float* __restrict__ traj,
    const float* __restrict__ eW, const float* __restrict__ eb,
    const float* __restrict__ oW, const float* __restrict__ ob,
    float* __restrict__ out) {
  __shared__ __align__(16) us wexp[3 * 128 * STR];
  __shared__ __align__(16) us owl[112 * STR];
  __shared__ __align__(16) us htile[4][16 * STR];
  __shared__ float ebl[384];
  __shared__ float obl[112];
  const int tid = threadIdx.x, wave = tid >> 6, lane = tid & 63;
  const int row16 = lane & 15, kg = lane >> 4;
  const int rbase = blockIdx.x * 64 + wave * 16;
  for (int i = tid; i < 12288; i += 256) {
    const int e = i >> 12, rem = i & 4095, o = rem >> 5, d4 = (rem & 31) * 4;
    const float4 v = *(const float4*)(eW + ((e * 128 + o) * 128 + d4));
    const unsigned lo = f2bf(v.x) | ((unsigned)f2bf(v.y) << 16);
    const unsigned hi = f2bf(v.z) | ((unsigned)f2bf(v.w) << 16);
    *(uint2*)&wexp[(e * 128 + o) * STR + d4] = make_uint2(lo, hi);
  }
  for (int i = tid; i < 112 * 32; i += 256) {
    const int cls = i >> 5, d4 = (i & 31) * 4;
    float4 v = make_float4(0.f, 0.f, 0.f, 0.f);
    if (cls < 100) v = *(const float4*)(oW + cls * 128 + d4);
    const unsigned lo = f2bf(v.x) | ((unsigned)f2bf(v.y) << 16);
    const unsigned hi = f2bf(v.z) | ((unsigned)f2bf(v.w) << 16);
    *(uint2*)&owl[cls * STR + d4] = make_uint2(lo, hi);
  }
  for (int i = tid; i < 384; i += 256) ebl[i] = eb[i];
  if (tid < 112) obl[tid] = (tid < 100) ? ob[tid] : 0.f;
  us* ht = &htile[wave][0];
  for (int i = lane; i < 256; i += 64) {
    const int row = i >> 4, d8 = (i & 15) * 8;
    const int rowg = rbase + row;
    const float4 v0 = *(const float4*)(h0 + (size_t)(rowg >> 1) * 128 + d8);
    const float4 v1 = *(const float4*)(h0 + (size_t)(rowg >> 1) * 128 + d8 + 4);
    uint4 p;
    p.x = f2bf(v0.x) | ((unsigned)f2bf(v0.y) << 16);
    p.y = f2bf(v0.z) | ((unsigned)f2bf(v0.w) << 16);
    p.z = f2bf(v1.x) | ((unsigned)f2bf(v1.y) << 16);
    p.w = f2bf(v1.z) | ((unsigned)f2bf(v1.w) << 16);
    *(uint4*)&ht[row * STR + d8] = p;
  }
  __syncthreads();
  float accv[8][4];
#pragma unroll
  for (int ct = 0; ct < 8; ++ct)
#pragma unroll
    for (int r = 0; r < 4; ++r) {
      const int rowg = rbase + kg * 4 + r;
      accv[ct][r] = h0[(size_t)(rowg >> 1) * 128 + ct * 16 + row16];
    }
  for (int d = 0; d < 3; ++d) {
    int sel[4];
#pragma unroll
    for (int r = 0; r < 4; ++r) {
      const int rowg = rbase + kg * 4 + r;
      const float4 t4 = *(const float4*)(traj + d * 16384 + rowg * 4);
      int s = 0; float mx = t4.x;
      if (t4.y > mx) { mx = t4.y; s = 1; }
      if (t4.z > mx) { mx = t4.z; s = 2; }
      if (t4.w > mx) { mx = t4.w; s = 3; }
      sel[r] = s;
    }
    s16x8 a[4];
#pragma unroll
    for (int kc = 0; kc < 4; ++kc)
      a[kc] = *(const s16x8*)&ht[row16 * STR + kc * 32 + kg * 8];
    float newacc[8][4];
#pragma unroll
    for (int ct = 0; ct < 8; ++ct)
#pragma unroll
      for (int r = 0; r < 4; ++r)
        newacc[ct][r] = (sel[r] == 3) ? accv[ct][r] : 0.f;
#pragma unroll
    for (int e = 0; e < 3; ++e) {
#pragma unroll
      for (int ct = 0; ct < 8; ++ct) {
        f32x4 t = {0.f, 0.f, 0.f, 0.f};
#pragma unroll
        for (int kc = 0; kc < 4; ++kc) {
          const s16x8 b = *(const s16x8*)&wexp[(e * 128 + ct * 16 + row16) * STR + kc * 32 + kg * 8];
          t = __builtin_amdgcn_mfma_f32_16x16x32_bf16(a[kc], b, t, 0, 0, 0);
        }
        const float bias = ebl[e * 128 + ct * 16 + row16];
#pragma unroll
        for (int r = 0; r < 4; ++r)
          if (sel[r] == e) newacc[ct][r] = t[r] + bias;
      }
    }
#pragma unroll
    for (int ct = 0; ct < 8; ++ct)
#pragma unroll
      for (int r = 0; r < 4; ++r) {
        float v = newacc[ct][r];
        if (d < 2) v = fmaxf(v, 0.f);
        accv[ct][r] = v;
        ht[(kg * 4 + r) * STR + ct * 16 + row16] = f2bf(v);
      }
  }
  s16x8 a[4];
#pragma unroll
  for (int kc = 0; kc < 4; ++kc)
    a[kc] = *(const s16x8*)&ht[row16 * STR + kc * 32 + kg * 8];
  float preds[7][4];
#pragma unroll
  for (int ct = 0; ct < 7; ++ct) {
    f32x4 t = {0.f, 0.f, 0.f, 0.f};
#pragma unroll
    for (int kc = 0; kc < 4; ++kc) {
      const s16x8 b = *(const s16x8*)&owl[(ct * 16 + row16) * STR + kc * 32 + kg * 8];
      t = __builtin_amdgcn_mfma_f32_16x16x32_bf16(a[kc], b, t, 0, 0, 0);
    }
    const float bias = obl[ct * 16 + row16];
#pragma unroll
    for (int r = 0; r < 4; ++r) preds[ct][r] = t[r] + bias;
  }
  const bool v6 = (96 + row16) < 100;
#pragma unroll
  for (int r = 0; r < 4; ++r) {
    float mx = -INFINITY;
#pragma unroll
    for (int ct = 0; ct < 7; ++ct)
      if (ct < 6 || v6) mx = fmaxf(mx, preds[ct][r]);
    mx = fmaxf(mx, __shfl_xor(mx, 1)); mx = fmaxf(mx, __shfl_xor(mx, 2));
    mx = fmaxf(mx, __shfl_xor(mx, 4)); mx = fmaxf(mx, __shfl_xor(mx, 8));
    float s = 0.f;
#pragma unroll
    for (int ct = 0; ct < 7; ++ct)
      if (ct < 6 || v6) s += expf(preds[ct][r] - mx);
    s += __shfl_xor(s, 1); s += __shfl_xor(s, 2);
    s += __shfl_xor(s, 4); s += __shfl_xor(s, 8);
    const float lg = mx + logf(s);
    const int rowg = rbase + kg * 4 + r;
#pragma unroll
    for (int ct = 0; ct < 7; ++ct)
      if (ct < 6 || v6) out[(size_t)rowg * 100 + ct * 16 + row16] = preds[ct][r] - lg;
  }
}

// ---------------------------------------------------------------- launch
extern "C" void kernel_launch(void* const* d_in, const int* in_sizes, int n_in,
                              void* d_out, int out_size, void* d_ws, size_t ws_size,
                              hipStream_t stream) {
  const float* x     = (const float*)d_in[0];
  const float* traj  = (const float*)d_in[1];
  const float* score = (const float*)d_in[2];
  const float* cw1 = (const float*)d_in[3];
  const float* cb1 = (const float*)d_in[4];
  const float* g1  = (const float*)d_in[5];
  const float* bb1 = (const float*)d_in[6];
  const float* cw2 = (const float*)d_in[7];
  const float* cb2 = (const float*)d_in[8];
  const float* g2  = (const float*)d_in[9];
  const float* bb2 = (const float*)d_in[10];
  const float* cw3 = (const float*)d_in[11];
  const float* cb3 = (const float*)d_in[12];
  const float* g3  = (const float*)d_in[13];
  const float* bb3 = (const float*)d_in[14];
  const float* eW  = (const float*)d_in[15];
  const float* eb  = (const float*)d_in[16];
  const float* oW  = (const float*)d_in[17];
  const float* ob  = (const float*)d_in[18];
  float* out = (float*)d_out;

  char* ws = (char*)d_ws;
  float* stats1 = (float*)ws;                    // 64 f32 {sc,sh}
  float* stats2 = (float*)(ws + 256);
  float* stats3 = (float*)(ws + 512);
  us* wt1L = (us*)(ws + 1024);
  us* wt2L = (us*)(ws + 4096);
  us* wt3L = (us*)(ws + 4096 + 23040);
  us* p1g  = (us*)(ws + 65536);                  // bf16 [2048][225][32]
  us* p2g  = (us*)(ws + 65536 + 29491200);       // bf16 [2048][36][32]
  float* h0g = (float*)(ws + 65536 + 29491200 + 4718592);  // f32 [2048][128]
  char* pbase = ws + 65536 + 29491200 + 4718592 + 1048576;
  float* part1 = (float*)pbase;                  // [64][2048]
  float* part2 = (float*)(pbase + 524288);
  float* part3 = (float*)(pbase + 1048576);

  prep_weights<<<12, 256, 0, stream>>>(cw1, cw2, cw3, wt1L, wt2L, wt3L);
  conv1_stats<<<2048, 256, 0, stream>>>(x, wt1L, cb1, part1);
  finalize_stats<<<32, 256, 0, stream>>>(part1, g1, bb1, 2048.f * 900.f, stats1);
  conv1_apply_conv2_stats<<<2048, 256, 0, stream>>>(x, wt1L, cb1, stats1,
                                                    wt2L, cb2, part2, p1g);
  finalize_stats<<<32, 256, 0, stream>>>(part2, g2, bb2, 2048.f * 169.f, stats2);
  conv2_apply_conv3_stats<<<2048, 256, 0, stream>>>(p1g, wt2L, cb2, stats2,
                                                    wt3L, cb3, part3, p2g);
  finalize_stats<<<32, 256, 0, stream>>>(part3, g3, bb3, 2048.f * 16.f, stats3);
  conv3_apply<<<256, 256, 0, stream>>>(p2g, wt3L, cb3, stats3, h0g);
  mlp2_kernel<<<64, 256, 0, stream>>>(h0g, traj, eW, eb, oW, ob, out);
  hipMemcpyAsync(out + 409600, score, 4096 * sizeof(float),
                 hipMemcpyDeviceToDevice, stream);
}

// Round 10
// 119.273 us; speedup vs baseline: 4.4919x; 1.0895x over previous
//
#include <hip/hip_runtime.h>
#include <math.h>

typedef unsigned short us;
typedef short s16x8 __attribute__((ext_vector_type(8)));
typedef float f32x4 __attribute__((ext_vector_type(4)));

#define EPSV 1e-5f

static __device__ inline us f2bf(float f) {            // RNE f32->bf16 (finite inputs)
  union { float f; unsigned u; } v; v.f = f;
  unsigned r = v.u + 0x7fffu + ((v.u >> 16) & 1u);
  return (us)(r >> 16);
}

union AU { s16x8 v; us e[8]; };

// ---------------------------------------------------------------- K0: preconvert weights
// conv1 tap-packed: wt1L[oc][40], col k: t=k>>2,c=k&3 -> w1[oc][c][t] (t<9,c<3) else 0
// wt1Lb[oc][40], col k<3 -> w1[oc][k][tap8] else 0
// wt2L/wt3L[(tap*32+oc)][40]; ewB[3*128*128] bf16; owB[112*128] bf16 zero-padded
__global__ __launch_bounds__(256) void prep_weights(
    const float* __restrict__ w1, const float* __restrict__ w2,
    const float* __restrict__ w3, const float* __restrict__ eW,
    const float* __restrict__ oW,
    us* __restrict__ wt1L, us* __restrict__ wt1Lb,
    us* __restrict__ wt2L, us* __restrict__ wt3L,
    us* __restrict__ ewB, us* __restrict__ owB) {
  const int gtid = blockIdx.x * 256 + threadIdx.x;
  const int G = gridDim.x * 256;
  for (int i = gtid; i < 1280; i += G) {
    const int oc = i / 40, k = i % 40, t = k >> 2, c = k & 3;
    wt1L[i] = (t < 9 && c < 3) ? f2bf(w1[oc * 27 + c * 9 + t]) : (us)0;
    wt1Lb[i] = (k < 3) ? f2bf(w1[oc * 27 + k * 9 + 8]) : (us)0;
  }
  for (int i = gtid; i < 11520; i += G) {
    const int row = i / 40, col = i % 40;
    const int tap = row >> 5, oc = row & 31;
    wt2L[i] = (col < 32) ? f2bf(w2[oc * 288 + col * 9 + tap]) : (us)0;
    wt3L[i] = (col < 32) ? f2bf(w3[oc * 288 + col * 9 + tap]) : (us)0;
  }
  for (int i = gtid; i < 49152; i += G) ewB[i] = f2bf(eW[i]);
  for (int i = gtid; i < 14336; i += G) {
    const int cls = i >> 7;
    owB[i] = (cls < 100) ? f2bf(oW[cls * 128 + (i & 127)]) : (us)0;
  }
}

// ---------------------------------------------------------------- finalize: partials[ch][2048] -> {scale, shift}
__global__ __launch_bounds__(256) void finalize_stats(
    const float* __restrict__ part, const float* __restrict__ g,
    const float* __restrict__ bb, float cnt, float* __restrict__ stats) {
  __shared__ float redS[256], redQ[256];
  const int ch = blockIdx.x, tid = threadIdx.x;
  const float* ps = part + (size_t)ch * 2048;
  const float* pq = part + (size_t)(32 + ch) * 2048;
  float s = 0.f, q = 0.f;
  for (int i = tid; i < 2048; i += 256) { s += ps[i]; q += pq[i]; }
  redS[tid] = s; redQ[tid] = q;
  __syncthreads();
  for (int off = 128; off; off >>= 1) {
    if (tid < off) { redS[tid] += redS[tid + off]; redQ[tid] += redQ[tid + off]; }
    __syncthreads();
  }
  if (tid == 0) {
    const float mean = redS[0] / cnt;
    const float var = redQ[0] / cnt - mean * mean;
    const float sc = g[ch] * rsqrtf(var + EPSV);
    stats[ch] = sc;
    stats[32 + ch] = bb[ch] - mean * sc;
  }
}

// conv1 shared helpers: stage x c-minor [32][32][4] bf16
static __device__ inline void stage_x_cminor(const float* xp, us* xsb4, int tid) {
#pragma unroll
  for (int k = 0; k < 4; ++k) {
    const int p = tid + k * 256;
    const float v0 = xp[p], v1 = xp[1024 + p], v2 = xp[2048 + p];
    const unsigned lo = f2bf(v0) | ((unsigned)f2bf(v1) << 16);
    const unsigned hi = (unsigned)f2bf(v2);
    *(uint2*)&xsb4[p * 4] = make_uint2(lo, hi);
  }
}

// ---------------------------------------------------------------- K1: conv1 stats only (tap-packed)
__global__ __launch_bounds__(256) void conv1_stats(
    const float* __restrict__ x, const us* __restrict__ wt1L,
    const us* __restrict__ wt1Lb, const float* __restrict__ cb,
    float* __restrict__ part1) {
  __shared__ __align__(16) us xsb4[4096];     // [32][32][4]
  __shared__ float csum[32], css[32];
  const int n = blockIdx.x, tid = threadIdx.x;
  const int wave = tid >> 6, lane = tid & 63, row16 = lane & 15, kg = lane >> 4;
  stage_x_cminor(x + (size_t)n * 3072, xsb4, tid);
  if (tid < 32) { csum[tid] = 0.f; css[tid] = 0.f; }
  __syncthreads();
  const int t0 = 2 * kg, t1 = 2 * kg + 1;
  const int toff0 = ((t0 / 3) * 32 + t0 % 3) * 4;
  const int toff1 = ((t1 / 3) * 32 + t1 % 3) * 4;
  const s16x8 bf0 = *(const s16x8*)&wt1L[row16 * 40 + kg * 8];
  const s16x8 bf1 = *(const s16x8*)&wt1L[(16 + row16) * 40 + kg * 8];
  const s16x8 bb0 = *(const s16x8*)&wt1Lb[row16 * 40 + kg * 8];
  const s16x8 bb1 = *(const s16x8*)&wt1Lb[(16 + row16) * 40 + kg * 8];
  const float bias0 = cb[row16], bias1 = cb[16 + row16];
  float s0 = 0.f, ss0 = 0.f, s1 = 0.f, ss1 = 0.f;
  for (int mt = wave; mt < 57; mt += 4) {     // permuted rows: q = window*4 + elem
    const int pixA = mt * 16 + row16;
    int boff = 0;
    if (pixA < 900) {
      const int w = pixA >> 2, e = pixA & 3;
      boff = ((2 * (w / 15) + (e >> 1)) * 32 + 2 * (w % 15) + (e & 1)) * 4;
    }
    AU a;
    *(uint2*)&a.e[0] = *(const uint2*)&xsb4[boff + toff0];
    *(uint2*)&a.e[4] = *(const uint2*)&xsb4[boff + toff1];
    AU a2;
#pragma unroll
    for (int j = 0; j < 8; ++j) a2.e[j] = 0;
    if (kg == 0) *(uint2*)&a2.e[0] = *(const uint2*)&xsb4[boff + 264];  // tap8 (ki=2,kj=2)
    f32x4 acc0 = {bias0, bias0, bias0, bias0};
    f32x4 acc1 = {bias1, bias1, bias1, bias1};
    acc0 = __builtin_amdgcn_mfma_f32_16x16x32_bf16(a.v, bf0, acc0, 0, 0, 0);
    acc0 = __builtin_amdgcn_mfma_f32_16x16x32_bf16(a2.v, bb0, acc0, 0, 0, 0);
    acc1 = __builtin_amdgcn_mfma_f32_16x16x32_bf16(a.v, bf1, acc1, 0, 0, 0);
    acc1 = __builtin_amdgcn_mfma_f32_16x16x32_bf16(a2.v, bb1, acc1, 0, 0, 0);
#pragma unroll
    for (int r = 0; r < 4; ++r) {
      const int pix = mt * 16 + kg * 4 + r;
      if (pix < 900) {
        s0 += acc0[r]; ss0 += acc0[r] * acc0[r];
        s1 += acc1[r]; ss1 += acc1[r] * acc1[r];
      }
    }
  }
  s0 += __shfl_down(s0, 32); s0 += __shfl_down(s0, 16);
  ss0 += __shfl_down(ss0, 32); ss0 += __shfl_down(ss0, 16);
  s1 += __shfl_down(s1, 32); s1 += __shfl_down(s1, 16);
  ss1 += __shfl_down(ss1, 32); ss1 += __shfl_down(ss1, 16);
  if (lane < 16) {
    atomicAdd(&csum[row16], s0); atomicAdd(&css[row16], ss0);
    atomicAdd(&csum[16 + row16], s1); atomicAdd(&css[16 + row16], ss1);
  }
  __syncthreads();
  if (tid < 32) {
    part1[tid * 2048 + n] = csum[tid];
    part1[(32 + tid) * 2048 + n] = css[tid];
  }
}

// ---------------------------------------------------------------- K2: conv1 (tap-packed, window-permuted) + bn1+relu+pool1 -> p1 + conv2 partials
__global__ __launch_bounds__(256) void conv1_apply_conv2_stats(
    const float* __restrict__ x, const us* __restrict__ wt1L,
    const us* __restrict__ wt1Lb, const float* __restrict__ cb1,
    const float* __restrict__ stats1,
    const us* __restrict__ wt2L, const float* __restrict__ cb2,
    float* __restrict__ part2, us* __restrict__ p1g) {
  __shared__ __align__(16) us xsb4[4096];
  __shared__ __align__(16) us p1b[9000];      // [225][40]
  __shared__ float scS[32], shS[32], csum[32], css[32];
  const int n = blockIdx.x, tid = threadIdx.x;
  const int wave = tid >> 6, lane = tid & 63, row16 = lane & 15, kg = lane >> 4;
  stage_x_cminor(x + (size_t)n * 3072, xsb4, tid);
  if (tid < 32) {
    scS[tid] = stats1[tid]; shS[tid] = stats1[32 + tid];
    csum[tid] = 0.f; css[tid] = 0.f;
  }
  __syncthreads();
  {
    const int t0 = 2 * kg, t1 = 2 * kg + 1;
    const int toff0 = ((t0 / 3) * 32 + t0 % 3) * 4;
    const int toff1 = ((t1 / 3) * 32 + t1 % 3) * 4;
    const s16x8 bf0 = *(const s16x8*)&wt1L[row16 * 40 + kg * 8];
    const s16x8 bf1 = *(const s16x8*)&wt1L[(16 + row16) * 40 + kg * 8];
    const s16x8 bb0 = *(const s16x8*)&wt1Lb[row16 * 40 + kg * 8];
    const s16x8 bb1 = *(const s16x8*)&wt1Lb[(16 + row16) * 40 + kg * 8];
    const float bias0 = cb1[row16], bias1 = cb1[16 + row16];
    const float sc0 = scS[row16], sh0 = shS[row16];
    const float sc1 = scS[16 + row16], sh1 = shS[16 + row16];
    for (int mt = wave; mt < 57; mt += 4) {
      const int pixA = mt * 16 + row16;
      int boff = 0;
      if (pixA < 900) {
        const int w = pixA >> 2, e = pixA & 3;
        boff = ((2 * (w / 15) + (e >> 1)) * 32 + 2 * (w % 15) + (e & 1)) * 4;
      }
      AU a;
      *(uint2*)&a.e[0] = *(const uint2*)&xsb4[boff + toff0];
      *(uint2*)&a.e[4] = *(const uint2*)&xsb4[boff + toff1];
      AU a2;
#pragma unroll
      for (int j = 0; j < 8; ++j) a2.e[j] = 0;
      if (kg == 0) *(uint2*)&a2.e[0] = *(const uint2*)&xsb4[boff + 264];
      f32x4 acc0 = {bias0, bias0, bias0, bias0};
      f32x4 acc1 = {bias1, bias1, bias1, bias1};
      acc0 = __builtin_amdgcn_mfma_f32_16x16x32_bf16(a.v, bf0, acc0, 0, 0, 0);
      acc0 = __builtin_amdgcn_mfma_f32_16x16x32_bf16(a2.v, bb0, acc0, 0, 0, 0);
      acc1 = __builtin_amdgcn_mfma_f32_16x16x32_bf16(a.v, bf1, acc1, 0, 0, 0);
      acc1 = __builtin_amdgcn_mfma_f32_16x16x32_bf16(a2.v, bb1, acc1, 0, 0, 0);
      const int w = mt * 4 + kg;              // pooled pixel 0..224
      if (w < 225) {
        float p0 = 0.f, p1v = 0.f;
#pragma unroll
        for (int r = 0; r < 4; ++r) {
          p0 += fmaxf(acc0[r] * sc0 + sh0, 0.f);
          p1v += fmaxf(acc1[r] * sc1 + sh1, 0.f);
        }
        p1b[w * 40 + row16] = f2bf(p0 * 0.25f);
        p1b[w * 40 + 16 + row16] = f2bf(p1v * 0.25f);
      }
    }
  }
  __syncthreads();
  // write p1 (bf16) coalesced
  for (int i = tid; i < 900; i += 256) {
    const uint4 v = *(const uint4*)&p1b[(i >> 2) * 40 + (i & 3) * 8];
    *(uint4*)(p1g + (size_t)n * 7200 + i * 8) = v;
  }
  // conv2 stats from LDS p1 (full 169 raster); B-fragments direct from global
  int inb[3];
#pragma unroll
  for (int m = 0; m < 3; ++m) {
    int pixA = (wave + 4 * m) * 16 + row16;
    if (pixA >= 169) pixA = 0;
    const int oi = pixA / 13, oj = pixA - 13 * oi;
    inb[m] = oi * 15 + oj;
  }
  const float b20 = cb2[row16], b21 = cb2[16 + row16];
  f32x4 acc[3][2];
#pragma unroll
  for (int m = 0; m < 3; ++m) {
    acc[m][0] = {b20, b20, b20, b20};
    acc[m][1] = {b21, b21, b21, b21};
  }
#pragma unroll
  for (int tap = 0; tap < 9; ++tap) {
    const int ki = tap / 3, kj = tap % 3;
    const s16x8 bf0 = *(const s16x8*)&wt2L[(tap * 32 + row16) * 40 + kg * 8];
    const s16x8 bf1 = *(const s16x8*)&wt2L[(tap * 32 + 16 + row16) * 40 + kg * 8];
#pragma unroll
    for (int m = 0; m < 3; ++m) {
      const s16x8 a = *(const s16x8*)&p1b[(inb[m] + ki * 15 + kj) * 40 + kg * 8];
      acc[m][0] = __builtin_amdgcn_mfma_f32_16x16x32_bf16(a, bf0, acc[m][0], 0, 0, 0);
      acc[m][1] = __builtin_amdgcn_mfma_f32_16x16x32_bf16(a, bf1, acc[m][1], 0, 0, 0);
    }
  }
  float s0 = 0.f, ss0 = 0.f, s1 = 0.f, ss1 = 0.f;
#pragma unroll
  for (int m = 0; m < 3; ++m)
#pragma unroll
    for (int r = 0; r < 4; ++r) {
      const int pix = (wave + 4 * m) * 16 + kg * 4 + r;
      if (pix < 169) {
        const float u0 = acc[m][0][r], u1 = acc[m][1][r];
        s0 += u0; ss0 += u0 * u0; s1 += u1; ss1 += u1 * u1;
      }
    }
  s0 += __shfl_down(s0, 32); s0 += __shfl_down(s0, 16);
  ss0 += __shfl_down(ss0, 32); ss0 += __shfl_down(ss0, 16);
  s1 += __shfl_down(s1, 32); s1 += __shfl_down(s1, 16);
  ss1 += __shfl_down(ss1, 32); ss1 += __shfl_down(ss1, 16);
  if (lane < 16) {
    atomicAdd(&csum[row16], s0); atomicAdd(&css[row16], ss0);
    atomicAdd(&csum[16 + row16], s1); atomicAdd(&css[16 + row16], ss1);
  }
  __syncthreads();
  if (tid < 32) {
    part2[tid * 2048 + n] = csum[tid];
    part2[(32 + tid) * 2048 + n] = css[tid];
  }
}

// ---------------------------------------------------------------- K3: conv2 (window-permuted) + bn2+relu+pool2 -> p2 + conv3 partials
__global__ __launch_bounds__(256) void conv2_apply_conv3_stats(
    const us* __restrict__ p1g, const us* __restrict__ wt2L,
    const float* __restrict__ cb2, const float* __restrict__ stats2,
    const us* __restrict__ wt3L, const float* __restrict__ cb3,
    float* __restrict__ part3, us* __restrict__ p2g) {
  __shared__ __align__(16) us p1b[9000];      // [225][40]
  __shared__ __align__(16) us p2b[1440];      // [36][40] pooled bf16
  __shared__ float scS[32], shS[32], csum[32], css[32];
  const int n = blockIdx.x, tid = threadIdx.x;
  const int wave = tid >> 6, lane = tid & 63, row16 = lane & 15, kg = lane >> 4;
  for (int i = tid; i < 900; i += 256) {
    const uint4 v = *(const uint4*)(p1g + (size_t)n * 7200 + i * 8);
    *(uint4*)&p1b[(i >> 2) * 40 + (i & 3) * 8] = v;
  }
  if (tid < 32) {
    scS[tid] = stats2[tid]; shS[tid] = stats2[32 + tid];
    csum[tid] = 0.f; css[tid] = 0.f;
  }
  __syncthreads();
  int inb[3], mtv[3];
#pragma unroll
  for (int m = 0; m < 3; ++m) {
    const int mt = wave + 4 * m;
    mtv[m] = mt;
    const int pixA = (mt < 9) ? (mt * 16 + row16) : row16;
    const int w = pixA >> 2, e = pixA & 3;
    const int oi = 2 * (w / 6) + (e >> 1), oj = 2 * (w % 6) + (e & 1);
    inb[m] = oi * 15 + oj;
  }
  const float b20 = cb2[row16], b21 = cb2[16 + row16];
  f32x4 acc[3][2];
#pragma unroll
  for (int m = 0; m < 3; ++m) {
    acc[m][0] = {b20, b20, b20, b20};
    acc[m][1] = {b21, b21, b21, b21};
  }
#pragma unroll
  for (int tap = 0; tap < 9; ++tap) {
    const int ki = tap / 3, kj = tap % 3;
    const s16x8 bf0 = *(const s16x8*)&wt2L[(tap * 32 + row16) * 40 + kg * 8];
    const s16x8 bf1 = *(const s16x8*)&wt2L[(tap * 32 + 16 + row16) * 40 + kg * 8];
#pragma unroll
    for (int m = 0; m < 3; ++m) {
      if (mtv[m] < 9) {
        const s16x8 a = *(const s16x8*)&p1b[(inb[m] + ki * 15 + kj) * 40 + kg * 8];
        acc[m][0] = __builtin_amdgcn_mfma_f32_16x16x32_bf16(a, bf0, acc[m][0], 0, 0, 0);
        acc[m][1] = __builtin_amdgcn_mfma_f32_16x16x32_bf16(a, bf1, acc[m][1], 0, 0, 0);
      }
    }
  }
  const float sc0 = scS[row16], sh0 = shS[row16];
  const float sc1 = scS[16 + row16], sh1 = shS[16 + row16];
#pragma unroll
  for (int m = 0; m < 3; ++m) {
    if (mtv[m] < 9) {
      float p0 = 0.f, p1v = 0.f;
#pragma unroll
      for (int r = 0; r < 4; ++r) {
        p0 += fmaxf(acc[m][0][r] * sc0 + sh0, 0.f);
        p1v += fmaxf(acc[m][1][r] * sc1 + sh1, 0.f);
      }
      const int wl = mtv[m] * 4 + kg;
      p2b[wl * 40 + row16] = f2bf(p0 * 0.25f);
      p2b[wl * 40 + 16 + row16] = f2bf(p1v * 0.25f);
    }
  }
  __syncthreads();
  if (tid < 144) {
    const int row = tid >> 2, col = (tid & 3) * 8;
    const uint4 v = *(const uint4*)&p2b[row * 40 + col];
    *(uint4*)(p2g + (size_t)n * 1152 + tid * 8) = v;
  }
  __syncthreads();
  if (wave < 2) {                              // conv3 stats
    const int ocb = wave * 16;
    const int inb3 = (row16 >> 2) * 6 + (row16 & 3);
    const float b3 = cb3[ocb + row16];
    f32x4 a3 = {b3, b3, b3, b3};
#pragma unroll
    for (int tap = 0; tap < 9; ++tap) {
      const int ki = tap / 3, kj = tap % 3;
      const s16x8 bf = *(const s16x8*)&wt3L[(tap * 32 + ocb + row16) * 40 + kg * 8];
      const s16x8 a = *(const s16x8*)&p2b[(inb3 + ki * 6 + kj) * 40 + kg * 8];
      a3 = __builtin_amdgcn_mfma_f32_16x16x32_bf16(a, bf, a3, 0, 0, 0);
    }
    float s = a3[0] + a3[1] + a3[2] + a3[3];
    float ss = a3[0]*a3[0] + a3[1]*a3[1] + a3[2]*a3[2] + a3[3]*a3[3];
    s += __shfl_down(s, 32); s += __shfl_down(s, 16);
    ss += __shfl_down(ss, 32); ss += __shfl_down(ss, 16);
    if (lane < 16) { atomicAdd(&csum[ocb + row16], s); atomicAdd(&css[ocb + row16], ss); }
  }
  __syncthreads();
  if (tid < 32) {
    part3[tid * 2048 + n] = csum[tid];
    part3[(32 + tid) * 2048 + n] = css[tid];
  }
}

// ---------------------------------------------------------------- K4: conv3 (window-permuted) + bn3+relu+pool3 -> h0 (8 samples/block)
__global__ __launch_bounds__(256) void conv3_apply(
    const us* __restrict__ p2g, const us* __restrict__ wt3L,
    const float* __restrict__ cb3, const float* __restrict__ stats3,
    float* __restrict__ h0g) {
  __shared__ __align__(16) us p2L[11520];      // [8][36][40]
  __shared__ float scS[32], shS[32];
  __shared__ float h0a[1024];
  const int n0 = blockIdx.x * 8, tid = threadIdx.x;
  const int wave = tid >> 6, lane = tid & 63, row16 = lane & 15, kg = lane >> 4;
  for (int i = tid; i < 1152; i += 256) {
    const int s = i / 144, ci = i - s * 144;
    const uint4 v = *(const uint4*)(p2g + (size_t)n0 * 1152 + i * 8);
    *(uint4*)&p2L[(s * 36 + (ci >> 2)) * 40 + (ci & 3) * 8] = v;
  }
  if (tid < 32) { scS[tid] = stats3[tid]; shS[tid] = stats3[32 + tid]; }
  __syncthreads();
  const int wA = row16 >> 2, eA = row16 & 3;
  const int inb3 = (2 * (wA >> 1) + (eA >> 1)) * 6 + 2 * (wA & 1) + (eA & 1);
  const float b30 = cb3[row16], b31 = cb3[16 + row16];
  f32x4 accA[2][2];
#pragma unroll
  for (int si = 0; si < 2; ++si) {
    accA[si][0] = {b30, b30, b30, b30};
    accA[si][1] = {b31, b31, b31, b31};
  }
#pragma unroll
  for (int tap = 0; tap < 9; ++tap) {
    const int ki = tap / 3, kj = tap % 3;
    const s16x8 bf0 = *(const s16x8*)&wt3L[(tap * 32 + row16) * 40 + kg * 8];
    const s16x8 bf1 = *(const s16x8*)&wt3L[(tap * 32 + 16 + row16) * 40 + kg * 8];
#pragma unroll
    for (int si = 0; si < 2; ++si) {
      const int s = wave + 4 * si;
      const s16x8 a = *(const s16x8*)&p2L[(s * 36 + inb3 + ki * 6 + kj) * 40 + kg * 8];
      accA[si][0] = __builtin_amdgcn_mfma_f32_16x16x32_bf16(a, bf0, accA[si][0], 0, 0, 0);
      accA[si][1] = __builtin_amdgcn_mfma_f32_16x16x32_bf16(a, bf1, accA[si][1], 0, 0, 0);
    }
  }
  const float sc0 = scS[row16], sh0 = shS[row16];
  const float sc1 = scS[16 + row16], sh1 = shS[16 + row16];
#pragma unroll
  for (int si = 0; si < 2; ++si) {
    const int s = wave + 4 * si;
    float p0 = 0.f, p1v = 0.f;
#pragma unroll
    for (int r = 0; r < 4; ++r) {
      p0 += fmaxf(accA[si][0][r] * sc0 + sh0, 0.f);
      p1v += fmaxf(accA[si][1][r] * sc1 + sh1, 0.f);
    }
    h0a[s * 128 + row16 * 4 + kg] = p0 * 0.25f;
    h0a[s * 128 + (16 + row16) * 4 + kg] = p1v * 0.25f;
  }
  __syncthreads();
  ((float4*)(h0g + (size_t)n0 * 128))[tid] = ((const float4*)h0a)[tid];
}

// ---------------------------------------------------------------- K5: MFMA routed MLP, weights from L2 (256 blocks x 1 wave x 16 rows)
__global__ __launch_bounds__(64) void mlp3_kernel(
    const float* __restrict__ h0, const float* __restrict__ traj,
    const us* __restrict__ ewB, const float* __restrict__ eb,
    const us* __restrict__ owB, const float* __restrict__ ob,
    float* __restrict__ out) {
  __shared__ __align__(16) us ht[16 * 136];
  __shared__ float ebl[384], obl[112];
  const int lane = threadIdx.x, row16 = lane & 15, kg = lane >> 4;
  const int rbase = blockIdx.x * 16;
  for (int i = lane; i < 384; i += 64) ebl[i] = eb[i];
  for (int i = lane; i < 112; i += 64) obl[i] = (i < 100) ? ob[i] : 0.f;
  {
    const int hr = lane >> 2, hc = (lane & 3) * 32;   // 16 rows x 4 lanes x 32 floats
    const float* hp = h0 + (size_t)((rbase + hr) >> 1) * 128 + hc;
#pragma unroll
    for (int q = 0; q < 4; ++q) {
      const float4 a0 = ((const float4*)hp)[q * 2];
      const float4 a1 = ((const float4*)hp)[q * 2 + 1];
      uint4 p;
      p.x = f2bf(a0.x) | ((unsigned)f2bf(a0.y) << 16);
      p.y = f2bf(a0.z) | ((unsigned)f2bf(a0.w) << 16);
      p.z = f2bf(a1.x) | ((unsigned)f2bf(a1.y) << 16);
      p.w = f2bf(a1.z) | ((unsigned)f2bf(a1.w) << 16);
      *(uint4*)&ht[hr * 136 + hc + q * 8] = p;
    }
  }
  __syncthreads();
  float accv[8][4];
#pragma unroll
  for (int ct = 0; ct < 8; ++ct)
#pragma unroll
    for (int r = 0; r < 4; ++r) {
      const int rowg = rbase + kg * 4 + r;
      accv[ct][r] = h0[(size_t)(rowg >> 1) * 128 + ct * 16 + row16];
    }
  for (int d = 0; d < 3; ++d) {
    int sel[4];
#pragma unroll
    for (int r = 0; r < 4; ++r) {
      const int rowg = rbase + kg * 4 + r;
      const float4 t4 = *(const float4*)(traj + d * 16384 + rowg * 4);
      int s = 0; float mx = t4.x;
      if (t4.y > mx) { mx = t4.y; s = 1; }
      if (t4.z > mx) { mx = t4.z; s = 2; }
      if (t4.w > mx) { mx = t4.w; s = 3; }
      sel[r] = s;
    }
    s16x8 a[4];
#pragma unroll
    for (int kc = 0; kc < 4; ++kc)
      a[kc] = *(const s16x8*)&ht[row16 * 136 + kc * 32 + kg * 8];
    float newacc[8][4];
#pragma unroll
    for (int ct = 0; ct < 8; ++ct)
#pragma unroll
      for (int r = 0; r < 4; ++r)
        newacc[ct][r] = (sel[r] == 3) ? accv[ct][r] : 0.f;
#pragma unroll
    for (int e = 0; e < 3; ++e) {
#pragma unroll
      for (int ct = 0; ct < 8; ++ct) {
        f32x4 t = {0.f, 0.f, 0.f, 0.f};
#pragma unroll
        for (int kc = 0; kc < 4; ++kc) {
          const s16x8 b = *(const s16x8*)&ewB[(e * 128 + ct * 16 + row16) * 128 + kc * 32 + kg * 8];
          t = __builtin_amdgcn_mfma_f32_16x16x32_bf16(a[kc], b, t, 0, 0, 0);
        }
        const float bias = ebl[e * 128 + ct * 16 + row16];
#pragma unroll
        for (int r = 0; r < 4; ++r)
          if (sel[r] == e) newacc[ct][r] = t[r] + bias;
      }
    }
#pragma unroll
    for (int ct = 0; ct < 8; ++ct)
#pragma unroll
      for (int r = 0; r < 4; ++r) {
        float v = newacc[ct][r];
        if (d < 2) v = fmaxf(v, 0.f);
        accv[ct][r] = v;
        ht[(kg * 4 + r) * 136 + ct * 16 + row16] = f2bf(v);   // same-wave LDS, in-order
      }
  }
  s16x8 a[4];
#pragma unroll
  for (int kc = 0; kc < 4; ++kc)
    a[kc] = *(const s16x8*)&ht[row16 * 136 + kc * 32 + kg * 8];
  float preds[7][4];
#pragma unroll
  for (int ct = 0; ct < 7; ++ct) {
    f32x4 t = {0.f, 0.f, 0.f, 0.f};
#pragma unroll
    for (int kc = 0; kc < 4; ++kc) {
      const s16x8 b = *(const s16x8*)&owB[(ct * 16 + row16) * 128 + kc * 32 + kg * 8];
      t = __builtin_amdgcn_mfma_f32_16x16x32_bf16(a[kc], b, t, 0, 0, 0);
    }
    const float bias = obl[ct * 16 + row16];
#pragma unroll
    for (int r = 0; r < 4; ++r) preds[ct][r] = t[r] + bias;
  }
  const bool v6 = (96 + row16) < 100;
#pragma unroll
  for (int r = 0; r < 4; ++r) {
    float mx = -INFINITY;
#pragma unroll
    for (int ct = 0; ct < 7; ++ct)
      if (ct < 6 || v6) mx = fmaxf(mx, preds[ct][r]);
    mx = fmaxf(mx, __shfl_xor(mx, 1)); mx = fmaxf(mx, __shfl_xor(mx, 2));
    mx = fmaxf(mx, __shfl_xor(mx, 4)); mx = fmaxf(mx, __shfl_xor(mx, 8));
    float s = 0.f;
#pragma unroll
    for (int ct = 0; ct < 7; ++ct)
      if (ct < 6 || v6) s += expf(preds[ct][r] - mx);
    s += __shfl_xor(s, 1); s += __shfl_xor(s, 2);
    s += __shfl_xor(s, 4); s += __shfl_xor(s, 8);
    const float lg = mx + logf(s);
    const int rowg = rbase + kg * 4 + r;
#pragma unroll
    for (int ct = 0; ct < 7; ++ct)
      if (ct < 6 || v6) out[(size_t)rowg * 100 + ct * 16 + row16] = preds[ct][r] - lg;
  }
}

// ---------------------------------------------------------------- launch
extern "C" void kernel_launch(void* const* d_in, const int* in_sizes, int n_in,
                              void* d_out, int out_size, void* d_ws, size_t ws_size,
                              hipStream_t stream) {
  const float* x     = (const float*)d_in[0];
  const float* traj  = (const float*)d_in[1];
  const float* score = (const float*)d_in[2];
  const float* cw1 = (const float*)d_in[3];
  const float* cb1 = (const float*)d_in[4];
  const float* g1  = (const float*)d_in[5];
  const float* bb1 = (const float*)d_in[6];
  const float* cw2 = (const float*)d_in[7];
  const float* cb2 = (const float*)d_in[8];
  const float* g2  = (const float*)d_in[9];
  const float* bb2 = (const float*)d_in[10];
  const float* cw3 = (const float*)d_in[11];
  const float* cb3 = (const float*)d_in[12];
  const float* g3  = (const float*)d_in[13];
  const float* bb3 = (const float*)d_in[14];
  const float* eW  = (const float*)d_in[15];
  const float* eb  = (const float*)d_in[16];
  const float* oW  = (const float*)d_in[17];
  const float* ob  = (const float*)d_in[18];
  float* out = (float*)d_out;

  char* ws = (char*)d_ws;
  float* stats1 = (float*)ws;                    // 64 f32 {sc,sh}
  float* stats2 = (float*)(ws + 256);
  float* stats3 = (float*)(ws + 512);
  us* wt1L  = (us*)(ws + 1024);                  // 1280 us
  us* wt1Lb = (us*)(ws + 4096);                  // 1280 us
  us* wt2L  = (us*)(ws + 8192);                  // 11520 us
  us* wt3L  = (us*)(ws + 8192 + 23040);          // 11520 us
  us* ewB   = (us*)(ws + 65536);                 // 49152 us = 98304 B
  us* owB   = (us*)(ws + 65536 + 98304);         // 14336 us = 28672 B
  us* p1g   = (us*)(ws + 262144);                // bf16 [2048][225][32] = 29,491,200 B
  us* p2g   = (us*)(ws + 262144 + 29491200);     // bf16 [2048][36][32]
  float* h0g = (float*)(ws + 262144 + 29491200 + 4718592);  // f32 [2048][128]
  char* pbase = ws + 262144 + 29491200 + 4718592 + 1048576;
  float* part1 = (float*)pbase;                  // [64][2048]
  float* part2 = (float*)(pbase + 524288);
  float* part3 = (float*)(pbase + 1048576);

  prep_weights<<<64, 256, 0, stream>>>(cw1, cw2, cw3, eW, oW,
                                       wt1L, wt1Lb, wt2L, wt3L, ewB, owB);
  conv1_stats<<<2048, 256, 0, stream>>>(x, wt1L, wt1Lb, cb1, part1);
  finalize_stats<<<32, 256, 0, stream>>>(part1, g1, bb1, 2048.f * 900.f, stats1);
  conv1_apply_conv2_stats<<<2048, 256, 0, stream>>>(x, wt1L, wt1Lb, cb1, stats1,
                                                    wt2L, cb2, part2, p1g);
  finalize_stats<<<32, 256, 0, stream>>>(part2, g2, bb2, 2048.f * 169.f, stats2);
  conv2_apply_conv3_stats<<<2048, 256, 0, stream>>>(p1g, wt2L, cb2, stats2,
                                                    wt3L, cb3, part3, p2g);
  finalize_stats<<<32, 256, 0, stream>>>(part3, g3, bb3, 2048.f * 16.f, stats3);
  conv3_apply<<<256, 256, 0, stream>>>(p2g, wt3L, cb3, stats3, h0g);
  mlp3_kernel<<<256, 64, 0, stream>>>(h0g, traj, ewB, eb, owB, ob, out);
  hipMemcpyAsync(out + 409600, score, 4096 * sizeof(float),
                 hipMemcpyDeviceToDevice, stream);
}